// Round 1
// baseline (21765.085 us; speedup 1.0000x reference)
//
#include <hip/hip_runtime.h>
#include <hip/hip_bf16.h>
#include <stdint.h>

// Seq2Seq GRU + attention, MI355X. Round 3: fast two-level flag grid barrier.
// Previous round's serialized atomicAdd barrier (~25-30us x 511 barriers) replaced
// with parallel flag arrival + block-0 gather + replicated-gen broadcast (~2-3us).

constexpr int cB = 16, cS = 128, cT = 128, cSTEPS = 127;
constexpr int cE = 256, cH = 512, cH2 = 1024, cH3 = 1536;
constexpr int cV = 32000, cKO = 1792, cMOUT = 2032, cMPAD = 2048;

typedef __attribute__((ext_vector_type(8))) short bf16x8;
typedef __attribute__((ext_vector_type(4))) float f32x4;

typedef const __attribute__((address_space(1))) void* as1cv;
typedef __attribute__((address_space(3))) void* as3v;
#define GLD16(g, l) __builtin_amdgcn_global_load_lds((as1cv)(g), (as3v)(l), 16, 0, 0)

__device__ __forceinline__ float sigm_(float x) { return 1.f / (1.f + __expf(-x)); }
__device__ __forceinline__ float tanh_(float x) {
  x = fminf(15.f, fmaxf(-15.f, x));
  float e = __expf(2.f * x);
  return (e - 1.f) / (e + 1.f);
}
__device__ __forceinline__ unsigned short f2bf(float x) {
  __hip_bfloat16 h = __float2bfloat16(x);
  union { __hip_bfloat16 b; unsigned short u; } cv; cv.b = h; return cv.u;
}
__device__ __forceinline__ float dot4_(float4 a, float4 b, float acc) {
  return fmaf(a.x, b.x, fmaf(a.y, b.y, fmaf(a.z, b.z, fmaf(a.w, b.w, acc))));
}

// Two-level flag grid barrier (cooperative launch, 256 blocks max).
// Layout at bar: flags[256] then gen[64] (4 replicas, 16-word = 64B apart).
// Arrival: parallel release-stores (no RMW chain). Gather: block 0, 255 threads
// acquire-poll in parallel. Broadcast: 4 replicated gen words split pollers.
__device__ __forceinline__ void gridbar(unsigned* bar, unsigned nblk, unsigned& g, unsigned blk) {
  unsigned* flags = bar;
  unsigned* gen = bar + 256;
  __syncthreads();
  g++;
  if (blk == 0) {
    for (unsigned i = threadIdx.x; i < nblk - 1; i += 256)
      while (__hip_atomic_load(&flags[i], __ATOMIC_ACQUIRE, __HIP_MEMORY_SCOPE_AGENT) < g)
        __builtin_amdgcn_s_sleep(1);
    __syncthreads();
    if (threadIdx.x == 0) {
      __threadfence();
#pragma unroll
      for (int r = 0; r < 4; r++)
        __hip_atomic_store(&gen[r * 16], g, __ATOMIC_RELEASE, __HIP_MEMORY_SCOPE_AGENT);
    }
  } else {
    if (threadIdx.x == 0) {
      __threadfence();
      __hip_atomic_store(&flags[blk - 1], g, __ATOMIC_RELEASE, __HIP_MEMORY_SCOPE_AGENT);
      unsigned* gp = &gen[(blk & 3) * 16];
      while (__hip_atomic_load(gp, __ATOMIC_ACQUIRE, __HIP_MEMORY_SCOPE_AGENT) < g)
        __builtin_amdgcn_s_sleep(1);
    }
    __syncthreads();
  }
}

__global__ void k_zero(unsigned* p, int n) {
  int i = blockIdx.x * blockDim.x + threadIdx.x;
  if (i < n) p[i] = 0u;
}

// ---------------- embeddings ----------------
__global__ void k_embed_enc(const int* __restrict__ src, const int* __restrict__ lens,
                            const float* __restrict__ tab,
                            float* __restrict__ emb, float* __restrict__ emb_rev) {
  int bs = blockIdx.x;          // b*S + s
  int b = bs >> 7, s = bs & 127;
  int e = threadIdx.x;
  int len = lens[b];
  int id  = src[b * cS + s];
  int rs  = (s < len) ? (len - 1 - s) : s;
  int id2 = src[b * cS + rs];
  emb[(size_t)bs * cE + e]     = tab[(size_t)id  * cE + e];
  emb_rev[(size_t)bs * cE + e] = tab[(size_t)id2 * cE + e];
}

__global__ void k_embed_dec(const int* __restrict__ tgt, const float* __restrict__ tab,
                            float* __restrict__ e_store) {
  int bt = blockIdx.x;          // b*STEPS + t
  int b = bt / cSTEPS, t = bt % cSTEPS;
  int id = tgt[b * cT + t];
  e_store[(size_t)bt * cE + threadIdx.x] = tab[(size_t)id * cE + threadIdx.x];
}

// ---------------- generic fp32 NT GEMM: C[M,N] = A[M,K] * B[N,K]^T (+bias_n)(tanh?) ----
#define GTM 128
#define GTN 64
#define GBK 16
__global__ __launch_bounds__(256) void k_gemm_nt_f32(
    const float* __restrict__ A, int lda, long asz,
    const float* __restrict__ Bm, int ldb, long bsz,
    float* __restrict__ C, int ldc, long csz,
    int M, int N, int K, const float* __restrict__ bias, int act) {
  __shared__ __align__(16) float As[GBK][GTM + 2];
  __shared__ __align__(16) float Bs[GBK][GTN + 2];
  int z = blockIdx.z;
  A  += (size_t)z * asz;
  Bm += (size_t)z * bsz;
  C  += (size_t)z * csz;
  int m0 = blockIdx.x * GTM, n0 = blockIdx.y * GTN;
  int tid = threadIdx.x;
  int ty = tid >> 4, tx = tid & 15;      // micro 8x4
  float acc[8][4];
#pragma unroll
  for (int i = 0; i < 8; i++)
#pragma unroll
    for (int j = 0; j < 4; j++) acc[i][j] = 0.f;

  int am = tid >> 1;            // 0..127
  int ak = (tid & 1) * 8;       // 0 or 8
  int bn = tid >> 2;            // 0..63
  int bk = (tid & 3) * 4;       // 0,4,8,12

  for (int k0 = 0; k0 < K; k0 += GBK) {
    __syncthreads();
    {
      int gm = m0 + am;
      if (gm < M) {
        const float* ap = A + (size_t)gm * lda + k0 + ak;
        float4 v0 = *(const float4*)ap;
        float4 v1 = *(const float4*)(ap + 4);
        As[ak + 0][am] = v0.x; As[ak + 1][am] = v0.y; As[ak + 2][am] = v0.z; As[ak + 3][am] = v0.w;
        As[ak + 4][am] = v1.x; As[ak + 5][am] = v1.y; As[ak + 6][am] = v1.z; As[ak + 7][am] = v1.w;
      } else {
#pragma unroll
        for (int i = 0; i < 8; i++) As[ak + i][am] = 0.f;
      }
      int gn = n0 + bn;
      if (gn < N) {
        const float* bp = Bm + (size_t)gn * ldb + k0 + bk;
        float4 v = *(const float4*)bp;
        Bs[bk + 0][bn] = v.x; Bs[bk + 1][bn] = v.y; Bs[bk + 2][bn] = v.z; Bs[bk + 3][bn] = v.w;
      } else {
#pragma unroll
        for (int i = 0; i < 4; i++) Bs[bk + i][bn] = 0.f;
      }
    }
    __syncthreads();
#pragma unroll
    for (int k = 0; k < GBK; k++) {
      float4 a0 = *(const float4*)&As[k][ty * 8];
      float4 a1 = *(const float4*)&As[k][ty * 8 + 4];
      float4 bv = *(const float4*)&Bs[k][tx * 4];
      float av[8] = {a0.x, a0.y, a0.z, a0.w, a1.x, a1.y, a1.z, a1.w};
      float bw[4] = {bv.x, bv.y, bv.z, bv.w};
#pragma unroll
      for (int i = 0; i < 8; i++)
#pragma unroll
        for (int j = 0; j < 4; j++) acc[i][j] = fmaf(av[i], bw[j], acc[i][j]);
    }
  }
  for (int i = 0; i < 8; i++) {
    int gm = m0 + ty * 8 + i;
    if (gm >= M) continue;
    for (int j = 0; j < 4; j++) {
      int gn = n0 + tx * 4 + j;
      if (gn >= N) continue;
      float v = acc[i][j];
      if (bias) v += bias[gn];
      if (act) v = tanh_(v);
      C[(size_t)gm * ldc + gn] = v;
    }
  }
}

// ---------------- cooperative encoder scan ----------------
// 256 blocks: blk>>7 = dir, (blk&127) owns 4 j's. 1 grid barrier / step.
__global__ __launch_bounds__(256) void k_enc_coop(
    const float* __restrict__ gi_f, const float* __restrict__ gi_b,
    const float* __restrict__ Whh_f, const float* __restrict__ Whh_b,
    const float* __restrict__ bhh_f, const float* __restrict__ bhh_b,
    const int* __restrict__ lens,
    float* __restrict__ enc_out, float* __restrict__ hcat,
    float* __restrict__ h_globE, unsigned* __restrict__ bar) {
  int blk = blockIdx.x, tid = threadIdx.x;
  int dir = blk >> 7, blkd = blk & 127;
  int j0 = blkd * 4;
  const float* gi  = dir ? gi_b  : gi_f;
  const float* Whh = dir ? Whh_b : Whh_f;
  const float* bhh = dir ? bhh_b : bhh_f;

  __shared__ __align__(16) float ls_w[12][cH];   // 24KB rows g*512+j0+jj at [g*4+jj]
  __shared__ __align__(16) float ls_h[cB][cH];   // 32KB
  __shared__ float ls_G[cB][12];                 // gh results

  for (int i = tid; i < 12 * cH; i += 256) {
    int ri = i >> 9, k = i & 511;
    int g = ri >> 2, jj = ri & 3;
    ls_w[ri][k] = Whh[(size_t)(g * cH + j0 + jj) * cH + k];
  }
  // init h_globE slice (disjoint per block)
  if (tid < 64) {
    int b = tid >> 2, jj = tid & 3;
    h_globE[dir * 8192 + b * cH + j0 + jj] = 0.f;
  }
  float br = 0.f, bz = 0.f, bn = 0.f; int lenv = 0;
  if (tid < 64) {
    int b = tid >> 2, j = j0 + (tid & 3);
    br = bhh[j]; bz = bhh[cH + j]; bn = bhh[2 * cH + j];
    lenv = lens[b];
  }
  unsigned g = 0;
  gridbar(bar, 256, g, blk);

  int kt = tid & 15, rt = (tid >> 4) & 3, bt = tid >> 6;
  const float* hsrc = h_globE + dir * 8192;
  float* hflat = &ls_h[0][0];

  for (int t = 0; t < cS; t++) {
    // stage h
    for (int i = tid * 4; i < 8192; i += 1024)
      *(float4*)&hflat[i] = *(const float4*)&hsrc[i];
    __syncthreads();
    // dots: thread (bt,rt,kt) -> 4 batches x 3 rows, k-range 32
    float acc[4][3];
#pragma unroll
    for (int i = 0; i < 4; i++)
#pragma unroll
      for (int jx = 0; jx < 3; jx++) acc[i][jx] = 0.f;
    int kbase = kt * 32;
#pragma unroll
    for (int k = 0; k < 32; k += 4) {
      float4 w0 = *(const float4*)&ls_w[rt * 3 + 0][kbase + k];
      float4 w1 = *(const float4*)&ls_w[rt * 3 + 1][kbase + k];
      float4 w2 = *(const float4*)&ls_w[rt * 3 + 2][kbase + k];
#pragma unroll
      for (int bs = 0; bs < 4; bs++) {
        float4 hv = *(const float4*)&ls_h[bt * 4 + bs][kbase + k];
        acc[bs][0] = dot4_(hv, w0, acc[bs][0]);
        acc[bs][1] = dot4_(hv, w1, acc[bs][1]);
        acc[bs][2] = dot4_(hv, w2, acc[bs][2]);
      }
    }
#pragma unroll
    for (int bs = 0; bs < 4; bs++)
#pragma unroll
      for (int r = 0; r < 3; r++) {
        float v = acc[bs][r];
        v += __shfl_down(v, 8, 16); v += __shfl_down(v, 4, 16);
        v += __shfl_down(v, 2, 16); v += __shfl_down(v, 1, 16);
        acc[bs][r] = v;
      }
    if (kt == 0) {
#pragma unroll
      for (int bs = 0; bs < 4; bs++)
#pragma unroll
        for (int r = 0; r < 3; r++)
          ls_G[bt * 4 + bs][rt * 3 + r] = acc[bs][r];
    }
    __syncthreads();
    // gates
    if (tid < 64) {
      int b = tid >> 2, jj = tid & 3, j = j0 + jj;
      const float* ge = gi + ((size_t)(b * cS + t)) * cH3;
      float ghr = ls_G[b][0 * 4 + jj];
      float ghz = ls_G[b][1 * 4 + jj];
      float ghn = ls_G[b][2 * 4 + jj];
      float r = sigm_(ge[j] + ghr + br);
      float z = sigm_(ge[cH + j] + ghz + bz);
      float n = tanh_(ge[2 * cH + j] + r * (ghn + bn));
      float hold = ls_h[b][j];
      float hnew = (1.f - z) * n + z * hold;
      bool valid = t < lenv;
      float hj = valid ? hnew : hold;
      int ts = dir ? (valid ? lenv - 1 - t : t) : t;
      enc_out[((size_t)(b * cS + ts)) * cH2 + dir * cH + j] = valid ? hnew : 0.f;
      h_globE[dir * 8192 + b * cH + j] = hj;
      if (t == cS - 1) hcat[b * cH2 + dir * cH + j] = hj;
    }
    gridbar(bar, 256, g, blk);
  }
}

// ---------------- cooperative decoder scan ----------------
// 256 blocks, each owns 2 j's. 3 grid barriers / step.
__global__ __launch_bounds__(256) void k_dec_coop(
    const float* __restrict__ hidden0,
    const float* __restrict__ gi_e,     // (B*STEPS,3H) incl b_ih_d
    const float* __restrict__ Pm,       // (B,3H,S)
    const float* __restrict__ encP,     // (B*S,H)
    const float* __restrict__ encT,     // (B,H2,S)
    const float* __restrict__ Wa_dec,   // (H,H)
    const float* __restrict__ Wv,       // (H)
    const float* __restrict__ Whh,      // (3H,H)
    const float* __restrict__ bhh,
    const int* __restrict__ lens,
    float* __restrict__ h_store,        // (B*STEPS,H)
    float* __restrict__ ctx_store,      // (B*STEPS,H2)
    float* __restrict__ h_glob,         // (B,H)
    float* __restrict__ dpsG,           // (B,H)
    float* __restrict__ energyG,        // (B,S)
    unsigned* __restrict__ bar) {
  int blk = blockIdx.x, tid = threadIdx.x;
  int j0 = blk * 2;

  __shared__ __align__(16) float ls_whh[6][cH];   // 12KB [jj*3+g]
  __shared__ __align__(16) float ls_wa[2][cH];    // 4KB
  __shared__ __align__(16) float ls_h[cB][cH];    // 32KB
  __shared__ __align__(16) float ls_att[cB][cS];  // 8KB
  __shared__ __align__(16) float ls_dpb[cH];      // 2KB (blocks<64)
  __shared__ float ls_red[cB][16];
  __shared__ float ls_mx[cB], ls_sum[cB];
  __shared__ float ls_A[cB][2][4];                // [b][jj][{dp,r,z,n}] (1..3 used)
  __shared__ float ls_C[cB][2][3];                // gi_ctx

  for (int i = tid; i < 6 * cH; i += 256) {
    int ri = i >> 9, k = i & 511;
    int jj = ri / 3, gg = ri % 3;
    ls_whh[ri][k] = Whh[(size_t)(gg * cH + j0 + jj) * cH + k];
  }
  for (int i = tid; i < 2 * cH; i += 256)
    ls_wa[i >> 9][i & 511] = Wa_dec[(size_t)(j0 + (i >> 9)) * cH + (i & 511)];
  if (tid < 32) {
    int b = tid >> 1, jj = tid & 1;
    h_glob[b * cH + j0 + jj] = hidden0[b * cH + j0 + jj];
  }
  float br = 0.f, bz = 0.f, bn = 0.f;
  if (tid < 32) {
    int j = j0 + (tid & 1);
    br = bhh[j]; bz = bhh[cH + j]; bn = bhh[2 * cH + j];
  }
  int lenB = (blk < 64) ? lens[blk >> 2] : 0;
  unsigned g = 0;
  gridbar(bar, 256, g, blk);

  int kt = tid & 15, ot = (tid >> 4) & 3, bt = tid >> 6;
  float* hflat = &ls_h[0][0];

  for (int t = 0; t < cSTEPS; t++) {
    // ---- phase A: dp + gh ----
    for (int i = tid * 4; i < 8192; i += 1024)
      *(float4*)&hflat[i] = *(const float4*)&h_glob[i];
    __syncthreads();
    {
      const float* w0 = (ot == 0) ? ls_wa[0] : ls_whh[0 * 3 + (ot - 1)];
      const float* w1 = (ot == 0) ? ls_wa[1] : ls_whh[1 * 3 + (ot - 1)];
      float acc[4][2];
#pragma unroll
      for (int i = 0; i < 4; i++) { acc[i][0] = 0.f; acc[i][1] = 0.f; }
      int kbase = kt * 32;
#pragma unroll
      for (int k = 0; k < 32; k += 4) {
        float4 wv0 = *(const float4*)&w0[kbase + k];
        float4 wv1 = *(const float4*)&w1[kbase + k];
#pragma unroll
        for (int bs = 0; bs < 4; bs++) {
          float4 hv = *(const float4*)&ls_h[bt * 4 + bs][kbase + k];
          acc[bs][0] = dot4_(hv, wv0, acc[bs][0]);
          acc[bs][1] = dot4_(hv, wv1, acc[bs][1]);
        }
      }
#pragma unroll
      for (int bs = 0; bs < 4; bs++)
#pragma unroll
        for (int jj = 0; jj < 2; jj++) {
          float v = acc[bs][jj];
          v += __shfl_down(v, 8, 16); v += __shfl_down(v, 4, 16);
          v += __shfl_down(v, 2, 16); v += __shfl_down(v, 1, 16);
          acc[bs][jj] = v;
        }
      if (kt == 0) {
#pragma unroll
        for (int bs = 0; bs < 4; bs++)
#pragma unroll
          for (int jj = 0; jj < 2; jj++) {
            int b = bt * 4 + bs;
            if (ot == 0) dpsG[b * cH + j0 + jj] = acc[bs][jj];
            else         ls_A[b][jj][ot] = acc[bs][jj];
          }
      }
    }
    gridbar(bar, 256, g, blk);

    // ---- phase B: energy (blocks 0..63; 4 per batch, 32 s each) ----
    if (blk < 64) {
      int bb = blk >> 2, sq = blk & 3;
      for (int i = tid; i < cH; i += 256) ls_dpb[i] = dpsG[bb * cH + i];
      __syncthreads();
      int sl = tid >> 3, k8 = tid & 7;
      int s = sq * 32 + sl;
      const float* ep  = encP + ((size_t)(bb * cS + s)) * cH + k8 * 64;
      const float* dpp = ls_dpb + k8 * 64;
      const float* wvp = Wv + k8 * 64;
      float e = 0.f;
#pragma unroll
      for (int k = 0; k < 64; k += 4) {
        float4 p  = *(const float4*)&ep[k];
        float4 d4 = *(const float4*)&dpp[k];
        float4 w4 = *(const float4*)&wvp[k];
        e = fmaf(w4.x, tanh_(p.x + d4.x), e);
        e = fmaf(w4.y, tanh_(p.y + d4.y), e);
        e = fmaf(w4.z, tanh_(p.z + d4.z), e);
        e = fmaf(w4.w, tanh_(p.w + d4.w), e);
      }
      e += __shfl_down(e, 4, 8); e += __shfl_down(e, 2, 8); e += __shfl_down(e, 1, 8);
      if (k8 == 0) energyG[bb * cS + s] = (s < lenB) ? e : -1e9f;
    }
    gridbar(bar, 256, g, blk);

    // ---- phase C: softmax (replicated) + ctx/gi_ctx + gates ----
    for (int i = tid; i < cB * cS; i += 256) ls_att[i >> 7][i & 127] = energyG[i];
    __syncthreads();
    {
      int sb = tid >> 4, su = tid & 15;
      float mx = -1e30f;
#pragma unroll
      for (int i = 0; i < 8; i++) mx = fmaxf(mx, ls_att[sb][su * 8 + i]);
      ls_red[sb][su] = mx;
      __syncthreads();
      if (su == 0) {
        float m = ls_red[sb][0];
#pragma unroll
        for (int i = 1; i < 16; i++) m = fmaxf(m, ls_red[sb][i]);
        ls_mx[sb] = m;
      }
      __syncthreads();
      float m = ls_mx[sb], ps = 0.f;
#pragma unroll
      for (int i = 0; i < 8; i++) {
        float e = __expf(ls_att[sb][su * 8 + i] - m);
        ls_att[sb][su * 8 + i] = e;
        ps += e;
      }
      __syncthreads();
      ls_red[sb][su] = ps;
      __syncthreads();
      if (su == 0) {
        float s = 0.f;
#pragma unroll
        for (int i = 0; i < 16; i++) s += ls_red[sb][i];
        ls_sum[sb] = 1.f / s;
      }
      __syncthreads();
      for (int i = tid; i < cB * cS; i += 256) {
        int bb2 = i >> 7;
        ls_att[bb2][i & 127] *= ls_sum[bb2];
      }
      __syncthreads();
    }
    // dots: 96 gi_ctx + 64 ctx
    if (tid < 160) {
      const float* rp;
      int b, jj = 0, gg = 0, d = 0;
      if (tid < 96) {
        b = tid / 6; int r6 = tid % 6; gg = r6 >> 1; jj = r6 & 1;
        rp = Pm + ((size_t)b * cH3 + gg * cH + j0 + jj) * cS;
      } else {
        int idx = tid - 96; b = idx >> 2; int dl = idx & 3; d = blk * 4 + dl;
        rp = encT + ((size_t)b * cH2 + d) * cS;
      }
      float a = 0.f;
#pragma unroll
      for (int k = 0; k < cS; k += 4) {
        float4 pv = *(const float4*)&rp[k];
        float4 av = *(const float4*)&ls_att[b][k];
        a = dot4_(pv, av, a);
      }
      if (tid < 96) ls_C[b][jj][gg] = a;
      else ctx_store[((size_t)b * cSTEPS + t) * cH2 + d] = a;
    }
    __syncthreads();
    // gates
    if (tid < 32) {
      int b = tid >> 1, jj = tid & 1, j = j0 + jj;
      size_t row = (size_t)b * cSTEPS + t;
      const float* ge = gi_e + row * cH3;
      float r = sigm_(ge[j] + ls_C[b][jj][0] + ls_A[b][jj][1] + br);
      float z = sigm_(ge[cH + j] + ls_C[b][jj][1] + ls_A[b][jj][2] + bz);
      float n = tanh_(ge[2 * cH + j] + ls_C[b][jj][2] + r * (ls_A[b][jj][3] + bn));
      float hold = ls_h[b][j];
      float hn = (1.f - z) * n + z * hold;
      h_glob[b * cH + j] = hn;
      h_store[row * cH + j] = hn;
    }
    gridbar(bar, 256, g, blk);
  }
}

// ---------------- transpose enc_out -> encT[b][d][s] ----------------
__global__ void k_transpose_enc(const float* __restrict__ enc_out, float* __restrict__ encT) {
  int bd = blockIdx.x;          // b*H2 + d
  int s = threadIdx.x;          // 128
  int b = bd >> 10, d = bd & 1023;
  encT[(size_t)bd * cS + s] = enc_out[(size_t)(b * cS + s) * cH2 + d];
}

// ---------------- build X (bf16) = [h ; ctx ; e], padded to 2048 rows ----------------
__global__ void k_build_x(const float* __restrict__ h_store, const float* __restrict__ ctx_store,
                          const float* __restrict__ e_store, unsigned short* __restrict__ Xb) {
  const int PAIRS = cMPAD * (cKO / 2);
  for (int idx = blockIdx.x * blockDim.x + threadIdx.x; idx < PAIRS; idx += gridDim.x * blockDim.x) {
    int m = idx / (cKO / 2);
    int k = (idx % (cKO / 2)) * 2;
    float2 v = make_float2(0.f, 0.f);
    if (m < cMOUT) {
      if (k < cH)            v = *(const float2*)&h_store[(size_t)m * cH + k];
      else if (k < cH + cH2) v = *(const float2*)&ctx_store[(size_t)m * cH2 + (k - cH)];
      else                   v = *(const float2*)&e_store[(size_t)m * cE + (k - cH - cH2)];
    }
    ushort2 o; o.x = f2bf(v.x); o.y = f2bf(v.y);
    *(ushort2*)(Xb + (size_t)idx * 2) = o;
  }
}

// ---------------- convert out_W to bf16 ----------------
__global__ void k_cvt_w(const float* __restrict__ Wf, unsigned short* __restrict__ Wb) {
  const int QUADS = cV * cKO / 4;
  for (int idx = blockIdx.x * blockDim.x + threadIdx.x; idx < QUADS; idx += gridDim.x * blockDim.x) {
    float4 v = *(const float4*)&Wf[(size_t)idx * 4];
    ushort4 o; o.x = f2bf(v.x); o.y = f2bf(v.y); o.z = f2bf(v.z); o.w = f2bf(v.w);
    *(ushort4*)(Wb + (size_t)idx * 4) = o;
  }
}

// ---------------- final bf16 MFMA GEMM ----------------
__global__ __launch_bounds__(256) void k_gemm_out(
    const unsigned short* __restrict__ Xb, const unsigned short* __restrict__ Wb,
    const float* __restrict__ bias, float* __restrict__ out) {
  __shared__ __align__(16) unsigned short As[128 * 32];
  __shared__ __align__(16) unsigned short Bs[128 * 32];
  int m0 = blockIdx.x * 128;
  int n0 = blockIdx.y * 128;
  int tid = threadIdx.x;
  int w = tid >> 6, l = tid & 63;
  int wm = (w >> 1) * 64, wn = (w & 1) * 64;
  int quad = l >> 4, lm = l & 15;
  f32x4 acc[4][4];
#pragma unroll
  for (int i = 0; i < 4; i++)
#pragma unroll
    for (int j = 0; j < 4; j++) acc[i][j] = (f32x4){0.f, 0.f, 0.f, 0.f};

  int c0 = tid, c1 = 256 + tid;
  int r0 = c0 >> 2, kc0 = (c0 & 3) * 8;
  int r1 = c1 >> 2, kc1 = (c1 & 3) * 8;
  const unsigned short* ga0 = Xb + (size_t)(m0 + r0) * cKO + kc0;
  const unsigned short* ga1 = Xb + (size_t)(m0 + r1) * cKO + kc1;
  const unsigned short* gb0 = Wb + (size_t)(n0 + r0) * cKO + kc0;
  const unsigned short* gb1 = Wb + (size_t)(n0 + r1) * cKO + kc1;
  unsigned short* la0 = As + (size_t)(w * 64) * 8;
  unsigned short* la1 = As + (size_t)(256 + w * 64) * 8;
  unsigned short* lb0 = Bs + (size_t)(w * 64) * 8;
  unsigned short* lb1 = Bs + (size_t)(256 + w * 64) * 8;

  for (int k0 = 0; k0 < cKO; k0 += 32) {
    __syncthreads();
    GLD16(ga0 + k0, la0);
    GLD16(ga1 + k0, la1);
    GLD16(gb0 + k0, lb0);
    GLD16(gb1 + k0, lb1);
    __syncthreads();
    bf16x8 af[4], bfr[4];
#pragma unroll
    for (int i = 0; i < 4; i++) {
      af[i]  = *(const bf16x8*)(As + (size_t)(wm + i * 16 + lm) * 32 + quad * 8);
      bfr[i] = *(const bf16x8*)(Bs + (size_t)(wn + i * 16 + lm) * 32 + quad * 8);
    }
#pragma unroll
    for (int i = 0; i < 4; i++)
#pragma unroll
      for (int j = 0; j < 4; j++)
        acc[i][j] = __builtin_amdgcn_mfma_f32_16x16x32_bf16(af[i], bfr[j], acc[i][j], 0, 0, 0);
  }
  for (int i = 0; i < 4; i++) {
    int gmb = m0 + wm + i * 16 + quad * 4;
    for (int j = 0; j < 4; j++) {
      int gn = n0 + wn + j * 16 + lm;
      float bv = bias[gn];
#pragma unroll
      for (int r = 0; r < 4; r++) {
        int gm = gmb + r;
        if (gm < cMOUT) out[(size_t)gm * cV + gn] = acc[i][j][r] + bv;
      }
    }
  }
}

extern "C" void kernel_launch(void* const* d_in, const int* in_sizes, int n_in,
                              void* d_out, int out_size, void* d_ws, size_t ws_size,
                              hipStream_t stream) {
  const int*   src      = (const int*)d_in[0];
  const int*   lens     = (const int*)d_in[1];
  const int*   tgt      = (const int*)d_in[2];
  const float* enc_emb  = (const float*)d_in[3];
  const float* W_ih_f   = (const float*)d_in[4];
  const float* W_hh_f   = (const float*)d_in[5];
  const float* b_ih_f   = (const float*)d_in[6];
  const float* b_hh_f   = (const float*)d_in[7];
  const float* W_ih_b   = (const float*)d_in[8];
  const float* W_hh_b   = (const float*)d_in[9];
  const float* b_ih_b   = (const float*)d_in[10];
  const float* b_hh_b   = (const float*)d_in[11];
  const float* bridge_W = (const float*)d_in[12];
  const float* bridge_b = (const float*)d_in[13];
  const float* dec_emb  = (const float*)d_in[14];
  const float* Wa_enc   = (const float*)d_in[15];
  const float* Wa_dec   = (const float*)d_in[16];
  const float* Wv       = (const float*)d_in[17];
  const float* W_ih_d   = (const float*)d_in[18];
  const float* W_hh_d   = (const float*)d_in[19];
  const float* b_ih_d   = (const float*)d_in[20];
  const float* b_hh_d   = (const float*)d_in[21];
  const float* out_W    = (const float*)d_in[22];
  const float* out_b    = (const float*)d_in[23];
  float* out = (float*)d_out;

  float* ws = (float*)d_ws;
  float* emb       = ws;                       // 16*128*256   (reused as aux after gi GEMMs)
  float* emb_rev   = emb + 524288;
  float* gi_f      = emb_rev + 524288;         // 16*128*1536
  float* gi_b      = gi_f + 3145728;
  float* enc_out   = gi_b + 3145728;           // 16*128*1024
  float* hcat      = enc_out + 2097152;        // 16*1024
  float* hidden0   = hcat + 16384;             // 16*512
  float* encP      = hidden0 + 8192;           // 16*128*512
  float* encT      = encP + 1048576;           // 16*1024*128
  float* Pm        = encT + 2097152;           // 16*1536*128
  float* gi_e      = Pm + 3145728;             // 16*127*1536
  float* e_store   = gi_e + 3121152;           // 16*127*256
  float* h_store   = e_store + 520192;         // 16*127*512
  float* ctx_store = h_store + 1040384;        // 16*127*1024
  unsigned short* Xb = (unsigned short*)(ctx_store + 2080768); // 2048*1792 bf16
  unsigned short* Wb = Xb + (size_t)2048 * 1792;               // 32000*1792 bf16

  // aux region reuses emb (dead after the gi GEMMs)
  float* h_globE = emb;              // 16384 (2 dirs x 16 x 512)
  float* h_glob  = emb + 16384;      // 8192
  float* dpsG    = emb + 24576;      // 8192
  float* energyG = emb + 32768;      // 2048
  unsigned* barE = (unsigned*)(emb + 34816);   // flags[256]+gen[64]
  unsigned* barD = barE + 320;                 // flags[256]+gen[64]

  // embeddings
  k_embed_enc<<<cB * cS, cE, 0, stream>>>(src, lens, enc_emb, emb, emb_rev);
  k_embed_dec<<<cB * cSTEPS, cE, 0, stream>>>(tgt, dec_emb, e_store);
  // encoder gi (both dirs)  — read emb/emb_rev
  k_gemm_nt_f32<<<dim3(16, 24, 1), 256, 0, stream>>>(emb, cE, 0, W_ih_f, cE, 0,
      gi_f, cH3, 0, cB * cS, cH3, cE, b_ih_f, 0);
  k_gemm_nt_f32<<<dim3(16, 24, 1), 256, 0, stream>>>(emb_rev, cE, 0, W_ih_b, cE, 0,
      gi_b, cH3, 0, cB * cS, cH3, cE, b_ih_b, 0);
  // barriers zeroed AFTER gi GEMMs (aux aliases emb)
  k_zero<<<3, 256, 0, stream>>>(barE, 640);
  // cooperative encoder scan
  {
    void* args[] = {(void*)&gi_f, (void*)&gi_b, (void*)&W_hh_f, (void*)&W_hh_b,
                    (void*)&b_hh_f, (void*)&b_hh_b, (void*)&lens, (void*)&enc_out,
                    (void*)&hcat, (void*)&h_globE, (void*)&barE};
    hipLaunchCooperativeKernel((void*)k_enc_coop, dim3(256), dim3(256), args, 0, stream);
  }
  // bridge -> hidden0 (tanh)
  k_gemm_nt_f32<<<dim3(1, 8, 1), 256, 0, stream>>>(hcat, cH2, 0, bridge_W, cH2, 0,
      hidden0, cH, 0, cB, cH, cH2, bridge_b, 1);
  // encP = enc_out @ Wa_enc^T
  k_gemm_nt_f32<<<dim3(16, 8, 1), 256, 0, stream>>>(enc_out, cH2, 0, Wa_enc, cH2, 0,
      encP, cH, 0, cB * cS, cH, cH2, nullptr, 0);
  // encT transpose
  k_transpose_enc<<<cB * cH2, cS, 0, stream>>>(enc_out, encT);
  // P[b] = W_ih_d[:,E:] @ enc_out[b]^T
  k_gemm_nt_f32<<<dim3(12, 2, 16), 256, 0, stream>>>(W_ih_d + cE, cE + cH2, 0,
      enc_out, cH2, (long)cS * cH2, Pm, cS, (long)cH3 * cS, cH3, cS, cH2, nullptr, 0);
  // gi_e = e @ W_ih_d[:,:E]^T + b_ih_d
  k_gemm_nt_f32<<<dim3(16, 24, 1), 256, 0, stream>>>(e_store, cE, 0, W_ih_d, cE + cH2, 0,
      gi_e, cH3, 0, cB * cSTEPS, cH3, cE, b_ih_d, 0);
  // cooperative decoder scan
  {
    void* args[] = {(void*)&hidden0, (void*)&gi_e, (void*)&Pm, (void*)&encP,
                    (void*)&encT, (void*)&Wa_dec, (void*)&Wv, (void*)&W_hh_d,
                    (void*)&b_hh_d, (void*)&lens, (void*)&h_store, (void*)&ctx_store,
                    (void*)&h_glob, (void*)&dpsG, (void*)&energyG, (void*)&barD};
    hipLaunchCooperativeKernel((void*)k_dec_coop, dim3(256), dim3(256), args, 0, stream);
  }
  // assemble X, convert W, big GEMM
  k_build_x<<<2048, 256, 0, stream>>>(h_store, ctx_store, e_store, Xb);
  k_cvt_w<<<4096, 256, 0, stream>>>(out_W, Wb);
  k_gemm_out<<<dim3(16, 250, 1), 256, 0, stream>>>(Xb, Wb, out_b, out);
}

// Round 6
// 9557.162 us; speedup vs baseline: 2.2774x; 2.2774x over previous
//
#include <hip/hip_runtime.h>
#include <hip/hip_bf16.h>
#include <stdint.h>

// Seq2Seq GRU + attention, MI355X. Round 8: RMW-poll grid barrier.
// History: R1 (acquire-poll barrier) PASSED @21.77ms but counters showed a per-poll
// buffer_inv storm (104GB fetch / 70GB write on k_dec_coop). R2/R4/R5 (relaxed-poll
// barrier) all failed/hung: RELAXED agent LOADS can be served stale from the
// non-coherent per-XCD L2 forever -> spin never exits. Fix per guide G16: poll with
// agent-scope atomic RMWs (fetch_add(p,0)) which execute at the MALL coherence point
// (always fresh, no cache ops), + exactly one __threadfence() per block per side.
// Everything else is the R1-verified 256x256 structure, unchanged.

constexpr int cB = 16, cS = 128, cT = 128, cSTEPS = 127;
constexpr int cE = 256, cH = 512, cH2 = 1024, cH3 = 1536;
constexpr int cV = 32000, cKO = 1792, cMOUT = 2032, cMPAD = 2048;

typedef __attribute__((ext_vector_type(8))) short bf16x8;
typedef __attribute__((ext_vector_type(4))) float f32x4;

typedef const __attribute__((address_space(1))) void* as1cv;
typedef __attribute__((address_space(3))) void* as3v;
#define GLD16(g, l) __builtin_amdgcn_global_load_lds((as1cv)(g), (as3v)(l), 16, 0, 0)

__device__ __forceinline__ float sigm_(float x) { return 1.f / (1.f + __expf(-x)); }
__device__ __forceinline__ float tanh_(float x) {
  x = fminf(15.f, fmaxf(-15.f, x));
  float e = __expf(2.f * x);
  return (e - 1.f) / (e + 1.f);
}
__device__ __forceinline__ unsigned short f2bf(float x) {
  __hip_bfloat16 h = __float2bfloat16(x);
  union { __hip_bfloat16 b; unsigned short u; } cv; cv.b = h; return cv.u;
}
__device__ __forceinline__ float dot4_(float4 a, float4 b, float acc) {
  return fmaf(a.x, b.x, fmaf(a.y, b.y, fmaf(a.z, b.z, fmaf(a.w, b.w, acc))));
}

// Coherent read via atomic RMW: executes at the MALL (memory-side, XCD-agnostic
// coherence point). Never served from stale local L2; emits no buffer_inv.
__device__ __forceinline__ unsigned rmw_read(unsigned* p) {
  return __hip_atomic_fetch_add(p, 0u, __ATOMIC_RELAXED, __HIP_MEMORY_SCOPE_AGENT);
}

// Grid barrier, RMW polling. Layout at bar: flags[256] then gen[64] (4 replicas,
// 64B apart; pollers split by blk&3). Arrival: one __threadfence() (wbl2 drains this
// XCD's dirty L2 to the coherence point) then fetch_add(flags[blk],1). Gather:
// block0's threads 1..255 RMW-poll flags in parallel. Broadcast: one fence (release
// block0's data + acquire others') then fetch_add on the 4 gen replicas. Pollers
// RMW-poll gen, then one __threadfence() (inv) so subsequent reads see fresh data.
__device__ __forceinline__ void gridbar(unsigned* bar, unsigned nblk, unsigned& g, unsigned blk) {
  unsigned* flags = bar;
  unsigned* gen = bar + 256;
  __syncthreads();   // all phase writes of this block drained to L2 (vmcnt(0) pre-barrier)
  g++;
  if (blk == 0) {
    if (threadIdx.x >= 1 && threadIdx.x < nblk) {
      while (rmw_read(&flags[threadIdx.x]) < g)
        __builtin_amdgcn_s_sleep(8);
    }
    __syncthreads();
    if (threadIdx.x == 0) {
      __threadfence();   // wbl2+inv: release block0's writes, acquire others' (their wbl2 preceded their flag)
#pragma unroll
      for (int r = 0; r < 4; r++)
        __hip_atomic_fetch_add(&gen[r * 16], 1u, __ATOMIC_RELAXED, __HIP_MEMORY_SCOPE_AGENT);
    }
    __syncthreads();
  } else {
    if (threadIdx.x == 0) {
      __threadfence();   // release: wbl2 this block's phase writes to coherence point
      __hip_atomic_fetch_add(&flags[blk], 1u, __ATOMIC_RELAXED, __HIP_MEMORY_SCOPE_AGENT);
      unsigned* gp = &gen[(blk & 3) * 16];
      while (rmw_read(gp) < g)
        __builtin_amdgcn_s_sleep(8);
      __threadfence();   // acquire: inv local L2 so post-barrier reads are fresh
    }
    __syncthreads();
  }
}

__global__ void k_zero(unsigned* p, int n) {
  int i = blockIdx.x * blockDim.x + threadIdx.x;
  if (i < n) p[i] = 0u;
}

// ---------------- embeddings ----------------
__global__ void k_embed_enc(const int* __restrict__ src, const int* __restrict__ lens,
                            const float* __restrict__ tab,
                            float* __restrict__ emb, float* __restrict__ emb_rev) {
  int bs = blockIdx.x;          // b*S + s
  int b = bs >> 7, s = bs & 127;
  int e = threadIdx.x;
  int len = lens[b];
  int id  = src[b * cS + s];
  int rs  = (s < len) ? (len - 1 - s) : s;
  int id2 = src[b * cS + rs];
  emb[(size_t)bs * cE + e]     = tab[(size_t)id  * cE + e];
  emb_rev[(size_t)bs * cE + e] = tab[(size_t)id2 * cE + e];
}

__global__ void k_embed_dec(const int* __restrict__ tgt, const float* __restrict__ tab,
                            float* __restrict__ e_store) {
  int bt = blockIdx.x;          // b*STEPS + t
  int b = bt / cSTEPS, t = bt % cSTEPS;
  int id = tgt[b * cT + t];
  e_store[(size_t)bt * cE + threadIdx.x] = tab[(size_t)id * cE + threadIdx.x];
}

// ---------------- generic fp32 NT GEMM: C[M,N] = A[M,K] * B[N,K]^T (+bias_n)(tanh?) ----
#define GTM 128
#define GTN 64
#define GBK 16
__global__ __launch_bounds__(256) void k_gemm_nt_f32(
    const float* __restrict__ A, int lda, long asz,
    const float* __restrict__ Bm, int ldb, long bsz,
    float* __restrict__ C, int ldc, long csz,
    int M, int N, int K, const float* __restrict__ bias, int act) {
  __shared__ __align__(16) float As[GBK][GTM + 2];
  __shared__ __align__(16) float Bs[GBK][GTN + 2];
  int z = blockIdx.z;
  A  += (size_t)z * asz;
  Bm += (size_t)z * bsz;
  C  += (size_t)z * csz;
  int m0 = blockIdx.x * GTM, n0 = blockIdx.y * GTN;
  int tid = threadIdx.x;
  int ty = tid >> 4, tx = tid & 15;      // micro 8x4
  float acc[8][4];
#pragma unroll
  for (int i = 0; i < 8; i++)
#pragma unroll
    for (int j = 0; j < 4; j++) acc[i][j] = 0.f;

  int am = tid >> 1;            // 0..127
  int ak = (tid & 1) * 8;       // 0 or 8
  int bn = tid >> 2;            // 0..63
  int bk = (tid & 3) * 4;       // 0,4,8,12

  for (int k0 = 0; k0 < K; k0 += GBK) {
    __syncthreads();
    {
      int gm = m0 + am;
      if (gm < M) {
        const float* ap = A + (size_t)gm * lda + k0 + ak;
        float4 v0 = *(const float4*)ap;
        float4 v1 = *(const float4*)(ap + 4);
        As[ak + 0][am] = v0.x; As[ak + 1][am] = v0.y; As[ak + 2][am] = v0.z; As[ak + 3][am] = v0.w;
        As[ak + 4][am] = v1.x; As[ak + 5][am] = v1.y; As[ak + 6][am] = v1.z; As[ak + 7][am] = v1.w;
      } else {
#pragma unroll
        for (int i = 0; i < 8; i++) As[ak + i][am] = 0.f;
      }
      int gn = n0 + bn;
      if (gn < N) {
        const float* bp = Bm + (size_t)gn * ldb + k0 + bk;
        float4 v = *(const float4*)bp;
        Bs[bk + 0][bn] = v.x; Bs[bk + 1][bn] = v.y; Bs[bk + 2][bn] = v.z; Bs[bk + 3][bn] = v.w;
      } else {
#pragma unroll
        for (int i = 0; i < 4; i++) Bs[bk + i][bn] = 0.f;
      }
    }
    __syncthreads();
#pragma unroll
    for (int k = 0; k < GBK; k++) {
      float4 a0 = *(const float4*)&As[k][ty * 8];
      float4 a1 = *(const float4*)&As[k][ty * 8 + 4];
      float4 bv = *(const float4*)&Bs[k][tx * 4];
      float av[8] = {a0.x, a0.y, a0.z, a0.w, a1.x, a1.y, a1.z, a1.w};
      float bw[4] = {bv.x, bv.y, bv.z, bv.w};
#pragma unroll
      for (int i = 0; i < 8; i++)
#pragma unroll
        for (int j = 0; j < 4; j++) acc[i][j] = fmaf(av[i], bw[j], acc[i][j]);
    }
  }
  for (int i = 0; i < 8; i++) {
    int gm = m0 + ty * 8 + i;
    if (gm >= M) continue;
    for (int j = 0; j < 4; j++) {
      int gn = n0 + tx * 4 + j;
      if (gn >= N) continue;
      float v = acc[i][j];
      if (bias) v += bias[gn];
      if (act) v = tanh_(v);
      C[(size_t)gm * ldc + gn] = v;
    }
  }
}

// ---------------- cooperative encoder scan ----------------
// 256 blocks: blk>>7 = dir, (blk&127) owns 4 j's. 1 grid barrier / step.
__global__ __launch_bounds__(256) void k_enc_coop(
    const float* __restrict__ gi_f, const float* __restrict__ gi_b,
    const float* __restrict__ Whh_f, const float* __restrict__ Whh_b,
    const float* __restrict__ bhh_f, const float* __restrict__ bhh_b,
    const int* __restrict__ lens,
    float* __restrict__ enc_out, float* __restrict__ hcat,
    float* __restrict__ h_globE, unsigned* __restrict__ bar) {
  int blk = blockIdx.x, tid = threadIdx.x;
  int dir = blk >> 7, blkd = blk & 127;
  int j0 = blkd * 4;
  const float* gi  = dir ? gi_b  : gi_f;
  const float* Whh = dir ? Whh_b : Whh_f;
  const float* bhh = dir ? bhh_b : bhh_f;

  __shared__ __align__(16) float ls_w[12][cH];   // 24KB rows g*512+j0+jj at [g*4+jj]
  __shared__ __align__(16) float ls_h[cB][cH];   // 32KB
  __shared__ float ls_G[cB][12];                 // gh results

  for (int i = tid; i < 12 * cH; i += 256) {
    int ri = i >> 9, k = i & 511;
    int g = ri >> 2, jj = ri & 3;
    ls_w[ri][k] = Whh[(size_t)(g * cH + j0 + jj) * cH + k];
  }
  // init h_globE slice (disjoint per block)
  if (tid < 64) {
    int b = tid >> 2, jj = tid & 3;
    h_globE[dir * 8192 + b * cH + j0 + jj] = 0.f;
  }
  float br = 0.f, bz = 0.f, bn = 0.f; int lenv = 0;
  if (tid < 64) {
    int b = tid >> 2, j = j0 + (tid & 3);
    br = bhh[j]; bz = bhh[cH + j]; bn = bhh[2 * cH + j];
    lenv = lens[b];
  }
  unsigned g = 0;
  gridbar(bar, 256, g, blk);

  int kt = tid & 15, rt = (tid >> 4) & 3, bt = tid >> 6;
  const float* hsrc = h_globE + dir * 8192;
  float* hflat = &ls_h[0][0];

  for (int t = 0; t < cS; t++) {
    // stage h
    for (int i = tid * 4; i < 8192; i += 1024)
      *(float4*)&hflat[i] = *(const float4*)&hsrc[i];
    __syncthreads();
    // dots: thread (bt,rt,kt) -> 4 batches x 3 rows, k-range 32
    float acc[4][3];
#pragma unroll
    for (int i = 0; i < 4; i++)
#pragma unroll
      for (int jx = 0; jx < 3; jx++) acc[i][jx] = 0.f;
    int kbase = kt * 32;
#pragma unroll
    for (int k = 0; k < 32; k += 4) {
      float4 w0 = *(const float4*)&ls_w[rt * 3 + 0][kbase + k];
      float4 w1 = *(const float4*)&ls_w[rt * 3 + 1][kbase + k];
      float4 w2 = *(const float4*)&ls_w[rt * 3 + 2][kbase + k];
#pragma unroll
      for (int bs = 0; bs < 4; bs++) {
        float4 hv = *(const float4*)&ls_h[bt * 4 + bs][kbase + k];
        acc[bs][0] = dot4_(hv, w0, acc[bs][0]);
        acc[bs][1] = dot4_(hv, w1, acc[bs][1]);
        acc[bs][2] = dot4_(hv, w2, acc[bs][2]);
      }
    }
#pragma unroll
    for (int bs = 0; bs < 4; bs++)
#pragma unroll
      for (int r = 0; r < 3; r++) {
        float v = acc[bs][r];
        v += __shfl_down(v, 8, 16); v += __shfl_down(v, 4, 16);
        v += __shfl_down(v, 2, 16); v += __shfl_down(v, 1, 16);
        acc[bs][r] = v;
      }
    if (kt == 0) {
#pragma unroll
      for (int bs = 0; bs < 4; bs++)
#pragma unroll
        for (int r = 0; r < 3; r++)
          ls_G[bt * 4 + bs][rt * 3 + r] = acc[bs][r];
    }
    __syncthreads();
    // gates
    if (tid < 64) {
      int b = tid >> 2, jj = tid & 3, j = j0 + jj;
      const float* ge = gi + ((size_t)(b * cS + t)) * cH3;
      float ghr = ls_G[b][0 * 4 + jj];
      float ghz = ls_G[b][1 * 4 + jj];
      float ghn = ls_G[b][2 * 4 + jj];
      float r = sigm_(ge[j] + ghr + br);
      float z = sigm_(ge[cH + j] + ghz + bz);
      float n = tanh_(ge[2 * cH + j] + r * (ghn + bn));
      float hold = ls_h[b][j];
      float hnew = (1.f - z) * n + z * hold;
      bool valid = t < lenv;
      float hj = valid ? hnew : hold;
      int ts = dir ? (valid ? lenv - 1 - t : t) : t;
      enc_out[((size_t)(b * cS + ts)) * cH2 + dir * cH + j] = valid ? hnew : 0.f;
      h_globE[dir * 8192 + b * cH + j] = hj;
      if (t == cS - 1) hcat[b * cH2 + dir * cH + j] = hj;
    }
    gridbar(bar, 256, g, blk);
  }
}

// ---------------- cooperative decoder scan ----------------
// 256 blocks, each owns 2 j's. 3 grid barriers / step.
__global__ __launch_bounds__(256) void k_dec_coop(
    const float* __restrict__ hidden0,
    const float* __restrict__ gi_e,     // (B*STEPS,3H) incl b_ih_d
    const float* __restrict__ Pm,       // (B,3H,S)
    const float* __restrict__ encP,     // (B*S,H)
    const float* __restrict__ encT,     // (B,H2,S)
    const float* __restrict__ Wa_dec,   // (H,H)
    const float* __restrict__ Wv,       // (H)
    const float* __restrict__ Whh,      // (3H,H)
    const float* __restrict__ bhh,
    const int* __restrict__ lens,
    float* __restrict__ h_store,        // (B*STEPS,H)
    float* __restrict__ ctx_store,      // (B*STEPS,H2)
    float* __restrict__ h_glob,         // (B,H)
    float* __restrict__ dpsG,           // (B,H)
    float* __restrict__ energyG,        // (B,S)
    unsigned* __restrict__ bar) {
  int blk = blockIdx.x, tid = threadIdx.x;
  int j0 = blk * 2;

  __shared__ __align__(16) float ls_whh[6][cH];   // 12KB [jj*3+g]
  __shared__ __align__(16) float ls_wa[2][cH];    // 4KB
  __shared__ __align__(16) float ls_h[cB][cH];    // 32KB
  __shared__ __align__(16) float ls_att[cB][cS];  // 8KB
  __shared__ __align__(16) float ls_dpb[cH];      // 2KB (blocks<64)
  __shared__ float ls_red[cB][16];
  __shared__ float ls_mx[cB], ls_sum[cB];
  __shared__ float ls_A[cB][2][4];                // [b][jj][{dp,r,z,n}] (1..3 used)
  __shared__ float ls_C[cB][2][3];                // gi_ctx

  for (int i = tid; i < 6 * cH; i += 256) {
    int ri = i >> 9, k = i & 511;
    int jj = ri / 3, gg = ri % 3;
    ls_whh[ri][k] = Whh[(size_t)(gg * cH + j0 + jj) * cH + k];
  }
  for (int i = tid; i < 2 * cH; i += 256)
    ls_wa[i >> 9][i & 511] = Wa_dec[(size_t)(j0 + (i >> 9)) * cH + (i & 511)];
  if (tid < 32) {
    int b = tid >> 1, jj = tid & 1;
    h_glob[b * cH + j0 + jj] = hidden0[b * cH + j0 + jj];
  }
  float br = 0.f, bz = 0.f, bn = 0.f;
  if (tid < 32) {
    int j = j0 + (tid & 1);
    br = bhh[j]; bz = bhh[cH + j]; bn = bhh[2 * cH + j];
  }
  int lenB = (blk < 64) ? lens[blk >> 2] : 0;
  unsigned g = 0;
  gridbar(bar, 256, g, blk);

  int kt = tid & 15, ot = (tid >> 4) & 3, bt = tid >> 6;
  float* hflat = &ls_h[0][0];

  for (int t = 0; t < cSTEPS; t++) {
    // ---- phase A: dp + gh ----
    for (int i = tid * 4; i < 8192; i += 1024)
      *(float4*)&hflat[i] = *(const float4*)&h_glob[i];
    __syncthreads();
    {
      const float* w0 = (ot == 0) ? ls_wa[0] : ls_whh[0 * 3 + (ot - 1)];
      const float* w1 = (ot == 0) ? ls_wa[1] : ls_whh[1 * 3 + (ot - 1)];
      float acc[4][2];
#pragma unroll
      for (int i = 0; i < 4; i++) { acc[i][0] = 0.f; acc[i][1] = 0.f; }
      int kbase = kt * 32;
#pragma unroll
      for (int k = 0; k < 32; k += 4) {
        float4 wv0 = *(const float4*)&w0[kbase + k];
        float4 wv1 = *(const float4*)&w1[kbase + k];
#pragma unroll
        for (int bs = 0; bs < 4; bs++) {
          float4 hv = *(const float4*)&ls_h[bt * 4 + bs][kbase + k];
          acc[bs][0] = dot4_(hv, wv0, acc[bs][0]);
          acc[bs][1] = dot4_(hv, wv1, acc[bs][1]);
        }
      }
#pragma unroll
      for (int bs = 0; bs < 4; bs++)
#pragma unroll
        for (int jj = 0; jj < 2; jj++) {
          float v = acc[bs][jj];
          v += __shfl_down(v, 8, 16); v += __shfl_down(v, 4, 16);
          v += __shfl_down(v, 2, 16); v += __shfl_down(v, 1, 16);
          acc[bs][jj] = v;
        }
      if (kt == 0) {
#pragma unroll
        for (int bs = 0; bs < 4; bs++)
#pragma unroll
          for (int jj = 0; jj < 2; jj++) {
            int b = bt * 4 + bs;
            if (ot == 0) dpsG[b * cH + j0 + jj] = acc[bs][jj];
            else         ls_A[b][jj][ot] = acc[bs][jj];
          }
      }
    }
    gridbar(bar, 256, g, blk);

    // ---- phase B: energy (blocks 0..63; 4 per batch, 32 s each) ----
    if (blk < 64) {
      int bb = blk >> 2, sq = blk & 3;
      for (int i = tid; i < cH; i += 256) ls_dpb[i] = dpsG[bb * cH + i];
      __syncthreads();
      int sl = tid >> 3, k8 = tid & 7;
      int s = sq * 32 + sl;
      const float* ep  = encP + ((size_t)(bb * cS + s)) * cH + k8 * 64;
      const float* dpp = ls_dpb + k8 * 64;
      const float* wvp = Wv + k8 * 64;
      float e = 0.f;
#pragma unroll
      for (int k = 0; k < 64; k += 4) {
        float4 p  = *(const float4*)&ep[k];
        float4 d4 = *(const float4*)&dpp[k];
        float4 w4 = *(const float4*)&wvp[k];
        e = fmaf(w4.x, tanh_(p.x + d4.x), e);
        e = fmaf(w4.y, tanh_(p.y + d4.y), e);
        e = fmaf(w4.z, tanh_(p.z + d4.z), e);
        e = fmaf(w4.w, tanh_(p.w + d4.w), e);
      }
      e += __shfl_down(e, 4, 8); e += __shfl_down(e, 2, 8); e += __shfl_down(e, 1, 8);
      if (k8 == 0) energyG[bb * cS + s] = (s < lenB) ? e : -1e9f;
    }
    gridbar(bar, 256, g, blk);

    // ---- phase C: softmax (replicated) + ctx/gi_ctx + gates ----
    for (int i = tid; i < cB * cS; i += 256) ls_att[i >> 7][i & 127] = energyG[i];
    __syncthreads();
    {
      int sb = tid >> 4, su = tid & 15;
      float mx = -1e30f;
#pragma unroll
      for (int i = 0; i < 8; i++) mx = fmaxf(mx, ls_att[sb][su * 8 + i]);
      ls_red[sb][su] = mx;
      __syncthreads();
      if (su == 0) {
        float m = ls_red[sb][0];
#pragma unroll
        for (int i = 1; i < 16; i++) m = fmaxf(m, ls_red[sb][i]);
        ls_mx[sb] = m;
      }
      __syncthreads();
      float m = ls_mx[sb], ps = 0.f;
#pragma unroll
      for (int i = 0; i < 8; i++) {
        float e = __expf(ls_att[sb][su * 8 + i] - m);
        ls_att[sb][su * 8 + i] = e;
        ps += e;
      }
      __syncthreads();
      ls_red[sb][su] = ps;
      __syncthreads();
      if (su == 0) {
        float s = 0.f;
#pragma unroll
        for (int i = 0; i < 16; i++) s += ls_red[sb][i];
        ls_sum[sb] = 1.f / s;
      }
      __syncthreads();
      for (int i = tid; i < cB * cS; i += 256) {
        int bb2 = i >> 7;
        ls_att[bb2][i & 127] *= ls_sum[bb2];
      }
      __syncthreads();
    }
    // dots: 96 gi_ctx + 64 ctx
    if (tid < 160) {
      const float* rp;
      int b, jj = 0, gg = 0, d = 0;
      if (tid < 96) {
        b = tid / 6; int r6 = tid % 6; gg = r6 >> 1; jj = r6 & 1;
        rp = Pm + ((size_t)b * cH3 + gg * cH + j0 + jj) * cS;
      } else {
        int idx = tid - 96; b = idx >> 2; int dl = idx & 3; d = blk * 4 + dl;
        rp = encT + ((size_t)b * cH2 + d) * cS;
      }
      float a = 0.f;
#pragma unroll
      for (int k = 0; k < cS; k += 4) {
        float4 pv = *(const float4*)&rp[k];
        float4 av = *(const float4*)&ls_att[b][k];
        a = dot4_(pv, av, a);
      }
      if (tid < 96) ls_C[b][jj][gg] = a;
      else ctx_store[((size_t)b * cSTEPS + t) * cH2 + d] = a;
    }
    __syncthreads();
    // gates
    if (tid < 32) {
      int b = tid >> 1, jj = tid & 1, j = j0 + jj;
      size_t row = (size_t)b * cSTEPS + t;
      const float* ge = gi_e + row * cH3;
      float r = sigm_(ge[j] + ls_C[b][jj][0] + ls_A[b][jj][1] + br);
      float z = sigm_(ge[cH + j] + ls_C[b][jj][1] + ls_A[b][jj][2] + bz);
      float n = tanh_(ge[2 * cH + j] + ls_C[b][jj][2] + r * (ls_A[b][jj][3] + bn));
      float hold = ls_h[b][j];
      float hn = (1.f - z) * n + z * hold;
      h_glob[b * cH + j] = hn;
      h_store[row * cH + j] = hn;
    }
    gridbar(bar, 256, g, blk);
  }
}

// ---------------- transpose enc_out -> encT[b][d][s] ----------------
__global__ void k_transpose_enc(const float* __restrict__ enc_out, float* __restrict__ encT) {
  int bd = blockIdx.x;          // b*H2 + d
  int s = threadIdx.x;          // 128
  int b = bd >> 10, d = bd & 1023;
  encT[(size_t)bd * cS + s] = enc_out[(size_t)(b * cS + s) * cH2 + d];
}

// ---------------- build X (bf16) = [h ; ctx ; e], padded to 2048 rows ----------------
__global__ void k_build_x(const float* __restrict__ h_store, const float* __restrict__ ctx_store,
                          const float* __restrict__ e_store, unsigned short* __restrict__ Xb) {
  const int PAIRS = cMPAD * (cKO / 2);
  for (int idx = blockIdx.x * blockDim.x + threadIdx.x; idx < PAIRS; idx += gridDim.x * blockDim.x) {
    int m = idx / (cKO / 2);
    int k = (idx % (cKO / 2)) * 2;
    float2 v = make_float2(0.f, 0.f);
    if (m < cMOUT) {
      if (k < cH)            v = *(const float2*)&h_store[(size_t)m * cH + k];
      else if (k < cH + cH2) v = *(const float2*)&ctx_store[(size_t)m * cH2 + (k - cH)];
      else                   v = *(const float2*)&e_store[(size_t)m * cE + (k - cH - cH2)];
    }
    ushort2 o; o.x = f2bf(v.x); o.y = f2bf(v.y);
    *(ushort2*)(Xb + (size_t)idx * 2) = o;
  }
}

// ---------------- convert out_W to bf16 ----------------
__global__ void k_cvt_w(const float* __restrict__ Wf, unsigned short* __restrict__ Wb) {
  const int QUADS = cV * cKO / 4;
  for (int idx = blockIdx.x * blockDim.x + threadIdx.x; idx < QUADS; idx += gridDim.x * blockDim.x) {
    float4 v = *(const float4*)&Wf[(size_t)idx * 4];
    ushort4 o; o.x = f2bf(v.x); o.y = f2bf(v.y); o.z = f2bf(v.z); o.w = f2bf(v.w);
    *(ushort4*)(Wb + (size_t)idx * 4) = o;
  }
}

// ---------------- final bf16 MFMA GEMM ----------------
__global__ __launch_bounds__(256) void k_gemm_out(
    const unsigned short* __restrict__ Xb, const unsigned short* __restrict__ Wb,
    const float* __restrict__ bias, float* __restrict__ out) {
  __shared__ __align__(16) unsigned short As[128 * 32];
  __shared__ __align__(16) unsigned short Bs[128 * 32];
  int m0 = blockIdx.x * 128;
  int n0 = blockIdx.y * 128;
  int tid = threadIdx.x;
  int w = tid >> 6, l = tid & 63;
  int wm = (w >> 1) * 64, wn = (w & 1) * 64;
  int quad = l >> 4, lm = l & 15;
  f32x4 acc[4][4];
#pragma unroll
  for (int i = 0; i < 4; i++)
#pragma unroll
    for (int j = 0; j < 4; j++) acc[i][j] = (f32x4){0.f, 0.f, 0.f, 0.f};

  int c0 = tid, c1 = 256 + tid;
  int r0 = c0 >> 2, kc0 = (c0 & 3) * 8;
  int r1 = c1 >> 2, kc1 = (c1 & 3) * 8;
  const unsigned short* ga0 = Xb + (size_t)(m0 + r0) * cKO + kc0;
  const unsigned short* ga1 = Xb + (size_t)(m0 + r1) * cKO + kc1;
  const unsigned short* gb0 = Wb + (size_t)(n0 + r0) * cKO + kc0;
  const unsigned short* gb1 = Wb + (size_t)(n0 + r1) * cKO + kc1;
  unsigned short* la0 = As + (size_t)(w * 64) * 8;
  unsigned short* la1 = As + (size_t)(256 + w * 64) * 8;
  unsigned short* lb0 = Bs + (size_t)(w * 64) * 8;
  unsigned short* lb1 = Bs + (size_t)(256 + w * 64) * 8;

  for (int k0 = 0; k0 < cKO; k0 += 32) {
    __syncthreads();
    GLD16(ga0 + k0, la0);
    GLD16(ga1 + k0, la1);
    GLD16(gb0 + k0, lb0);
    GLD16(gb1 + k0, lb1);
    __syncthreads();
    bf16x8 af[4], bfr[4];
#pragma unroll
    for (int i = 0; i < 4; i++) {
      af[i]  = *(const bf16x8*)(As + (size_t)(wm + i * 16 + lm) * 32 + quad * 8);
      bfr[i] = *(const bf16x8*)(Bs + (size_t)(wn + i * 16 + lm) * 32 + quad * 8);
    }
#pragma unroll
    for (int i = 0; i < 4; i++)
#pragma unroll
      for (int j = 0; j < 4; j++)
        acc[i][j] = __builtin_amdgcn_mfma_f32_16x16x32_bf16(af[i], bfr[j], acc[i][j], 0, 0, 0);
  }
  for (int i = 0; i < 4; i++) {
    int gmb = m0 + wm + i * 16 + quad * 4;
    for (int j = 0; j < 4; j++) {
      int gn = n0 + wn + j * 16 + lm;
      float bv = bias[gn];
#pragma unroll
      for (int r = 0; r < 4; r++) {
        int gm = gmb + r;
        if (gm < cMOUT) out[(size_t)gm * cV + gn] = acc[i][j][r] + bv;
      }
    }
  }
}

extern "C" void kernel_launch(void* const* d_in, const int* in_sizes, int n_in,
                              void* d_out, int out_size, void* d_ws, size_t ws_size,
                              hipStream_t stream) {
  const int*   src      = (const int*)d_in[0];
  const int*   lens     = (const int*)d_in[1];
  const int*   tgt      = (const int*)d_in[2];
  const float* enc_emb  = (const float*)d_in[3];
  const float* W_ih_f   = (const float*)d_in[4];
  const float* W_hh_f   = (const float*)d_in[5];
  const float* b_ih_f   = (const float*)d_in[6];
  const float* b_hh_f   = (const float*)d_in[7];
  const float* W_ih_b   = (const float*)d_in[8];
  const float* W_hh_b   = (const float*)d_in[9];
  const float* b_ih_b   = (const float*)d_in[10];
  const float* b_hh_b   = (const float*)d_in[11];
  const float* bridge_W = (const float*)d_in[12];
  const float* bridge_b = (const float*)d_in[13];
  const float* dec_emb  = (const float*)d_in[14];
  const float* Wa_enc   = (const float*)d_in[15];
  const float* Wa_dec   = (const float*)d_in[16];
  const float* Wv       = (const float*)d_in[17];
  const float* W_ih_d   = (const float*)d_in[18];
  const float* W_hh_d   = (const float*)d_in[19];
  const float* b_ih_d   = (const float*)d_in[20];
  const float* b_hh_d   = (const float*)d_in[21];
  const float* out_W    = (const float*)d_in[22];
  const float* out_b    = (const float*)d_in[23];
  float* out = (float*)d_out;

  float* ws = (float*)d_ws;
  float* emb       = ws;                       // 16*128*256   (reused as aux after gi GEMMs)
  float* emb_rev   = emb + 524288;
  float* gi_f      = emb_rev + 524288;         // 16*128*1536
  float* gi_b      = gi_f + 3145728;
  float* enc_out   = gi_b + 3145728;           // 16*128*1024
  float* hcat      = enc_out + 2097152;        // 16*1024
  float* hidden0   = hcat + 16384;             // 16*512
  float* encP      = hidden0 + 8192;           // 16*128*512
  float* encT      = encP + 1048576;           // 16*1024*128
  float* Pm        = encT + 2097152;           // 16*1536*128
  float* gi_e      = Pm + 3145728;             // 16*127*1536
  float* e_store   = gi_e + 3121152;           // 16*127*256
  float* h_store   = e_store + 520192;         // 16*127*512
  float* ctx_store = h_store + 1040384;        // 16*127*1024
  unsigned short* Xb = (unsigned short*)(ctx_store + 2080768); // 2048*1792 bf16
  unsigned short* Wb = Xb + (size_t)2048 * 1792;               // 32000*1792 bf16

  // aux region reuses emb (dead after the gi GEMMs)
  float* h_globE = emb;              // 16384 (2 dirs x 16 x 512)
  float* h_glob  = emb + 16384;      // 8192
  float* dpsG    = emb + 24576;      // 8192
  float* energyG = emb + 32768;      // 2048
  unsigned* barE = (unsigned*)(emb + 34816);   // flags[256]+gen[64]
  unsigned* barD = barE + 320;                 // flags[256]+gen[64]

  // embeddings
  k_embed_enc<<<cB * cS, cE, 0, stream>>>(src, lens, enc_emb, emb, emb_rev);
  k_embed_dec<<<cB * cSTEPS, cE, 0, stream>>>(tgt, dec_emb, e_store);
  // encoder gi (both dirs)  — read emb/emb_rev
  k_gemm_nt_f32<<<dim3(16, 24, 1), 256, 0, stream>>>(emb, cE, 0, W_ih_f, cE, 0,
      gi_f, cH3, 0, cB * cS, cH3, cE, b_ih_f, 0);
  k_gemm_nt_f32<<<dim3(16, 24, 1), 256, 0, stream>>>(emb_rev, cE, 0, W_ih_b, cE, 0,
      gi_b, cH3, 0, cB * cS, cH3, cE, b_ih_b, 0);
  // barriers zeroed AFTER gi GEMMs (aux aliases emb)
  k_zero<<<3, 256, 0, stream>>>(barE, 640);
  // cooperative encoder scan
  {
    void* args[] = {(void*)&gi_f, (void*)&gi_b, (void*)&W_hh_f, (void*)&W_hh_b,
                    (void*)&b_hh_f, (void*)&b_hh_b, (void*)&lens, (void*)&enc_out,
                    (void*)&hcat, (void*)&h_globE, (void*)&barE};
    hipLaunchCooperativeKernel((void*)k_enc_coop, dim3(256), dim3(256), args, 0, stream);
  }
  // bridge -> hidden0 (tanh)
  k_gemm_nt_f32<<<dim3(1, 8, 1), 256, 0, stream>>>(hcat, cH2, 0, bridge_W, cH2, 0,
      hidden0, cH, 0, cB, cH, cH2, bridge_b, 1);
  // encP = enc_out @ Wa_enc^T
  k_gemm_nt_f32<<<dim3(16, 8, 1), 256, 0, stream>>>(enc_out, cH2, 0, Wa_enc, cH2, 0,
      encP, cH, 0, cB * cS, cH, cH2, nullptr, 0);
  // encT transpose
  k_transpose_enc<<<cB * cH2, cS, 0, stream>>>(enc_out, encT);
  // P[b] = W_ih_d[:,E:] @ enc_out[b]^T
  k_gemm_nt_f32<<<dim3(12, 2, 16), 256, 0, stream>>>(W_ih_d + cE, cE + cH2, 0,
      enc_out, cH2, (long)cS * cH2, Pm, cS, (long)cH3 * cS, cH3, cS, cH2, nullptr, 0);
  // gi_e = e @ W_ih_d[:,:E]^T + b_ih_d
  k_gemm_nt_f32<<<dim3(16, 24, 1), 256, 0, stream>>>(e_store, cE, 0, W_ih_d, cE + cH2, 0,
      gi_e, cH3, 0, cB * cSTEPS, cH3, cE, b_ih_d, 0);
  // cooperative decoder scan
  {
    void* args[] = {(void*)&hidden0, (void*)&gi_e, (void*)&Pm, (void*)&encP,
                    (void*)&encT, (void*)&Wa_dec, (void*)&Wv, (void*)&W_hh_d,
                    (void*)&b_hh_d, (void*)&lens, (void*)&h_store, (void*)&ctx_store,
                    (void*)&h_glob, (void*)&dpsG, (void*)&energyG, (void*)&barD};
    hipLaunchCooperativeKernel((void*)k_dec_coop, dim3(256), dim3(256), args, 0, stream);
  }
  // assemble X, convert W, big GEMM
  k_build_x<<<2048, 256, 0, stream>>>(h_store, ctx_store, e_store, Xb);
  k_cvt_w<<<4096, 256, 0, stream>>>(out_W, Wb);
  k_gemm_out<<<dim3(16, 250, 1), 256, 0, stream>>>(Xb, Wb, out_b, out);
}

// Round 8
// 6536.052 us; speedup vs baseline: 3.3300x; 1.4622x over previous
//
#include <hip/hip_runtime.h>
#include <hip/hip_bf16.h>
#include <stdint.h>

// Seq2Seq GRU + attention, MI355X. Round 10 (= R9 resubmit; infra acquisition
// timeout last round, kernel never ran). Fence-free grid barrier + sc1 data path.
// R8 post-mortem: RMW polls fixed nothing about traffic (FETCH still 105GB == R1) ->
// the storm is the 2x __threadfence per block per barrier (each invalidates the XCD
// L2, forcing re-stream of Pm/encT/encP/gi_e every step). Fix: tiny mutable shared
// state (h_glob/dpsG/energyG, ~18KB/step) moves to agent-scope relaxed atomics
// (global_load/store sc1 -> coherence point, no L2 involvement); big read-only
// streams stay cached; barrier has NO fences (syncthreads drains vmcnt before flag).
// Polls = atomic loads with RMW fallback every 8th iter (progress guaranteed).
// Flags padded to 64B stride to kill same-line RMW serialization.

constexpr int cB = 16, cS = 128, cT = 128, cSTEPS = 127;
constexpr int cE = 256, cH = 512, cH2 = 1024, cH3 = 1536;
constexpr int cV = 32000, cKO = 1792, cMOUT = 2032, cMPAD = 2048;
constexpr int cBARSZ = 4096 + 64;   // flags[256*16] + gen[4*16]

typedef __attribute__((ext_vector_type(8))) short bf16x8;
typedef __attribute__((ext_vector_type(4))) float f32x4;

typedef const __attribute__((address_space(1))) void* as1cv;
typedef __attribute__((address_space(3))) void* as3v;
#define GLD16(g, l) __builtin_amdgcn_global_load_lds((as1cv)(g), (as3v)(l), 16, 0, 0)

__device__ __forceinline__ float sigm_(float x) { return 1.f / (1.f + __expf(-x)); }
__device__ __forceinline__ float tanh_(float x) {
  x = fminf(15.f, fmaxf(-15.f, x));
  float e = __expf(2.f * x);
  return (e - 1.f) / (e + 1.f);
}
__device__ __forceinline__ unsigned short f2bf(float x) {
  __hip_bfloat16 h = __float2bfloat16(x);
  union { __hip_bfloat16 b; unsigned short u; } cv; cv.b = h; return cv.u;
}
__device__ __forceinline__ float dot4_(float4 a, float4 b, float acc) {
  return fmaf(a.x, b.x, fmaf(a.y, b.y, fmaf(a.z, b.z, fmaf(a.w, b.w, acc))));
}

// Coherent scalar access to shared mutable state: agent-scope relaxed atomics lower
// to global_load/store with sc1 (L2-bypass to the memory-side coherence point).
__device__ __forceinline__ float cload(const float* p) {
  return __hip_atomic_load(p, __ATOMIC_RELAXED, __HIP_MEMORY_SCOPE_AGENT);
}
__device__ __forceinline__ void cstore(float* p, float v) {
  __hip_atomic_store(p, v, __ATOMIC_RELAXED, __HIP_MEMORY_SCOPE_AGENT);
}

// Fence-free grid barrier. flags stride-16 (64B) per block; gen 4 replicas 64B apart.
// Entry __syncthreads() drains vmcnt(0) -> this block's sc1 stores are acked at the
// coherence point before its flag store. Polls: atomic load (same-address loads don't
// serialize) with fetch_add fallback every 8th iter (guaranteed-fresh progress).
__device__ __forceinline__ void gridbar(unsigned* bar, unsigned nblk, unsigned& g, unsigned blk) {
  unsigned* flags = bar;
  unsigned* gen = bar + 4096;
  __syncthreads();
  g++;
  if (blk == 0) {
    if (threadIdx.x >= 1 && threadIdx.x < nblk) {
      unsigned* fp = &flags[threadIdx.x * 16];
      unsigned it = 0;
      for (;;) {
        unsigned v = ((++it) & 7u)
            ? __hip_atomic_load(fp, __ATOMIC_RELAXED, __HIP_MEMORY_SCOPE_AGENT)
            : __hip_atomic_fetch_add(fp, 0u, __ATOMIC_RELAXED, __HIP_MEMORY_SCOPE_AGENT);
        if (v >= g) break;
        __builtin_amdgcn_s_sleep(1);
      }
    }
    __syncthreads();
    if (threadIdx.x < 4)
      __hip_atomic_store(&gen[threadIdx.x * 16], g, __ATOMIC_RELAXED, __HIP_MEMORY_SCOPE_AGENT);
    __syncthreads();
  } else {
    if (threadIdx.x == 0) {
      __hip_atomic_store(&flags[blk * 16], g, __ATOMIC_RELAXED, __HIP_MEMORY_SCOPE_AGENT);
      unsigned* gp = &gen[(blk & 3u) * 16];
      unsigned it = 0;
      for (;;) {
        unsigned v = ((++it) & 7u)
            ? __hip_atomic_load(gp, __ATOMIC_RELAXED, __HIP_MEMORY_SCOPE_AGENT)
            : __hip_atomic_fetch_add(gp, 0u, __ATOMIC_RELAXED, __HIP_MEMORY_SCOPE_AGENT);
        if (v >= g) break;
        __builtin_amdgcn_s_sleep(1);
      }
    }
    __syncthreads();
  }
}

__global__ void k_zero(unsigned* p, int n) {
  int i = blockIdx.x * blockDim.x + threadIdx.x;
  if (i < n) p[i] = 0u;
}

// ---------------- embeddings ----------------
__global__ void k_embed_enc(const int* __restrict__ src, const int* __restrict__ lens,
                            const float* __restrict__ tab,
                            float* __restrict__ emb, float* __restrict__ emb_rev) {
  int bs = blockIdx.x;          // b*S + s
  int b = bs >> 7, s = bs & 127;
  int e = threadIdx.x;
  int len = lens[b];
  int id  = src[b * cS + s];
  int rs  = (s < len) ? (len - 1 - s) : s;
  int id2 = src[b * cS + rs];
  emb[(size_t)bs * cE + e]     = tab[(size_t)id  * cE + e];
  emb_rev[(size_t)bs * cE + e] = tab[(size_t)id2 * cE + e];
}

__global__ void k_embed_dec(const int* __restrict__ tgt, const float* __restrict__ tab,
                            float* __restrict__ e_store) {
  int bt = blockIdx.x;          // b*STEPS + t
  int b = bt / cSTEPS, t = bt % cSTEPS;
  int id = tgt[b * cT + t];
  e_store[(size_t)bt * cE + threadIdx.x] = tab[(size_t)id * cE + threadIdx.x];
}

// ---------------- generic fp32 NT GEMM: C[M,N] = A[M,K] * B[N,K]^T (+bias_n)(tanh?) ----
#define GTM 128
#define GTN 64
#define GBK 16
__global__ __launch_bounds__(256) void k_gemm_nt_f32(
    const float* __restrict__ A, int lda, long asz,
    const float* __restrict__ Bm, int ldb, long bsz,
    float* __restrict__ C, int ldc, long csz,
    int M, int N, int K, const float* __restrict__ bias, int act) {
  __shared__ __align__(16) float As[GBK][GTM + 2];
  __shared__ __align__(16) float Bs[GBK][GTN + 2];
  int z = blockIdx.z;
  A  += (size_t)z * asz;
  Bm += (size_t)z * bsz;
  C  += (size_t)z * csz;
  int m0 = blockIdx.x * GTM, n0 = blockIdx.y * GTN;
  int tid = threadIdx.x;
  int ty = tid >> 4, tx = tid & 15;      // micro 8x4
  float acc[8][4];
#pragma unroll
  for (int i = 0; i < 8; i++)
#pragma unroll
    for (int j = 0; j < 4; j++) acc[i][j] = 0.f;

  int am = tid >> 1;            // 0..127
  int ak = (tid & 1) * 8;       // 0 or 8
  int bn = tid >> 2;            // 0..63
  int bk = (tid & 3) * 4;       // 0,4,8,12

  for (int k0 = 0; k0 < K; k0 += GBK) {
    __syncthreads();
    {
      int gm = m0 + am;
      if (gm < M) {
        const float* ap = A + (size_t)gm * lda + k0 + ak;
        float4 v0 = *(const float4*)ap;
        float4 v1 = *(const float4*)(ap + 4);
        As[ak + 0][am] = v0.x; As[ak + 1][am] = v0.y; As[ak + 2][am] = v0.z; As[ak + 3][am] = v0.w;
        As[ak + 4][am] = v1.x; As[ak + 5][am] = v1.y; As[ak + 6][am] = v1.z; As[ak + 7][am] = v1.w;
      } else {
#pragma unroll
        for (int i = 0; i < 8; i++) As[ak + i][am] = 0.f;
      }
      int gn = n0 + bn;
      if (gn < N) {
        const float* bp = Bm + (size_t)gn * ldb + k0 + bk;
        float4 v = *(const float4*)bp;
        Bs[bk + 0][bn] = v.x; Bs[bk + 1][bn] = v.y; Bs[bk + 2][bn] = v.z; Bs[bk + 3][bn] = v.w;
      } else {
#pragma unroll
        for (int i = 0; i < 4; i++) Bs[bk + i][bn] = 0.f;
      }
    }
    __syncthreads();
#pragma unroll
    for (int k = 0; k < GBK; k++) {
      float4 a0 = *(const float4*)&As[k][ty * 8];
      float4 a1 = *(const float4*)&As[k][ty * 8 + 4];
      float4 bv = *(const float4*)&Bs[k][tx * 4];
      float av[8] = {a0.x, a0.y, a0.z, a0.w, a1.x, a1.y, a1.z, a1.w};
      float bw[4] = {bv.x, bv.y, bv.z, bv.w};
#pragma unroll
      for (int i = 0; i < 8; i++)
#pragma unroll
        for (int j = 0; j < 4; j++) acc[i][j] = fmaf(av[i], bw[j], acc[i][j]);
    }
  }
  for (int i = 0; i < 8; i++) {
    int gm = m0 + ty * 8 + i;
    if (gm >= M) continue;
    for (int j = 0; j < 4; j++) {
      int gn = n0 + tx * 4 + j;
      if (gn >= N) continue;
      float v = acc[i][j];
      if (bias) v += bias[gn];
      if (act) v = tanh_(v);
      C[(size_t)gm * ldc + gn] = v;
    }
  }
}

// ---------------- cooperative encoder scan ----------------
// 256 blocks: blk>>7 = dir, (blk&127) owns 4 j's. 1 grid barrier / step.
// h_globE is the only cross-block mutable state -> sc1 atomics.
__global__ __launch_bounds__(256) void k_enc_coop(
    const float* __restrict__ gi_f, const float* __restrict__ gi_b,
    const float* __restrict__ Whh_f, const float* __restrict__ Whh_b,
    const float* __restrict__ bhh_f, const float* __restrict__ bhh_b,
    const int* __restrict__ lens,
    float* __restrict__ enc_out, float* __restrict__ hcat,
    float* __restrict__ h_globE, unsigned* __restrict__ bar) {
  int blk = blockIdx.x, tid = threadIdx.x;
  int dir = blk >> 7, blkd = blk & 127;
  int j0 = blkd * 4;
  const float* gi  = dir ? gi_b  : gi_f;
  const float* Whh = dir ? Whh_b : Whh_f;
  const float* bhh = dir ? bhh_b : bhh_f;

  __shared__ __align__(16) float ls_w[12][cH];   // 24KB rows g*512+j0+jj at [g*4+jj]
  __shared__ __align__(16) float ls_h[cB][cH];   // 32KB
  __shared__ float ls_G[cB][12];                 // gh results

  for (int i = tid; i < 12 * cH; i += 256) {
    int ri = i >> 9, k = i & 511;
    int g = ri >> 2, jj = ri & 3;
    ls_w[ri][k] = Whh[(size_t)(g * cH + j0 + jj) * cH + k];
  }
  // init h_globE slice (disjoint per block)
  if (tid < 64) {
    int b = tid >> 2, jj = tid & 3;
    cstore(&h_globE[dir * 8192 + b * cH + j0 + jj], 0.f);
  }
  float br = 0.f, bz = 0.f, bn = 0.f; int lenv = 0;
  if (tid < 64) {
    int b = tid >> 2, j = j0 + (tid & 3);
    br = bhh[j]; bz = bhh[cH + j]; bn = bhh[2 * cH + j];
    lenv = lens[b];
  }
  unsigned g = 0;
  gridbar(bar, 256, g, blk);

  int kt = tid & 15, rt = (tid >> 4) & 3, bt = tid >> 6;
  const float* hsrc = h_globE + dir * 8192;
  float* hflat = &ls_h[0][0];

  for (int t = 0; t < cS; t++) {
    // stage h (coherent scalar loads, 32/thread)
    for (int i = tid; i < 8192; i += 256)
      hflat[i] = cload(&hsrc[i]);
    __syncthreads();
    // dots: thread (bt,rt,kt) -> 4 batches x 3 rows, k-range 32
    float acc[4][3];
#pragma unroll
    for (int i = 0; i < 4; i++)
#pragma unroll
      for (int jx = 0; jx < 3; jx++) acc[i][jx] = 0.f;
    int kbase = kt * 32;
#pragma unroll
    for (int k = 0; k < 32; k += 4) {
      float4 w0 = *(const float4*)&ls_w[rt * 3 + 0][kbase + k];
      float4 w1 = *(const float4*)&ls_w[rt * 3 + 1][kbase + k];
      float4 w2 = *(const float4*)&ls_w[rt * 3 + 2][kbase + k];
#pragma unroll
      for (int bs = 0; bs < 4; bs++) {
        float4 hv = *(const float4*)&ls_h[bt * 4 + bs][kbase + k];
        acc[bs][0] = dot4_(hv, w0, acc[bs][0]);
        acc[bs][1] = dot4_(hv, w1, acc[bs][1]);
        acc[bs][2] = dot4_(hv, w2, acc[bs][2]);
      }
    }
#pragma unroll
    for (int bs = 0; bs < 4; bs++)
#pragma unroll
      for (int r = 0; r < 3; r++) {
        float v = acc[bs][r];
        v += __shfl_down(v, 8, 16); v += __shfl_down(v, 4, 16);
        v += __shfl_down(v, 2, 16); v += __shfl_down(v, 1, 16);
        acc[bs][r] = v;
      }
    if (kt == 0) {
#pragma unroll
      for (int bs = 0; bs < 4; bs++)
#pragma unroll
        for (int r = 0; r < 3; r++)
          ls_G[bt * 4 + bs][rt * 3 + r] = acc[bs][r];
    }
    __syncthreads();
    // gates
    if (tid < 64) {
      int b = tid >> 2, jj = tid & 3, j = j0 + jj;
      const float* ge = gi + ((size_t)(b * cS + t)) * cH3;
      float ghr = ls_G[b][0 * 4 + jj];
      float ghz = ls_G[b][1 * 4 + jj];
      float ghn = ls_G[b][2 * 4 + jj];
      float r = sigm_(ge[j] + ghr + br);
      float z = sigm_(ge[cH + j] + ghz + bz);
      float n = tanh_(ge[2 * cH + j] + r * (ghn + bn));
      float hold = ls_h[b][j];
      float hnew = (1.f - z) * n + z * hold;
      bool valid = t < lenv;
      float hj = valid ? hnew : hold;
      int ts = dir ? (valid ? lenv - 1 - t : t) : t;
      enc_out[((size_t)(b * cS + ts)) * cH2 + dir * cH + j] = valid ? hnew : 0.f;
      cstore(&h_globE[dir * 8192 + b * cH + j], hj);
      if (t == cS - 1) hcat[b * cH2 + dir * cH + j] = hj;
    }
    gridbar(bar, 256, g, blk);
  }
}

// ---------------- cooperative decoder scan ----------------
// 256 blocks, each owns 2 j's. 3 grid barriers / step.
// h_glob/dpsG/energyG are cross-block mutable -> sc1 atomics. Pm/encT/encP/gi_e
// are read-only within the kernel -> normal cached loads (L2 stays warm now).
__global__ __launch_bounds__(256) void k_dec_coop(
    const float* __restrict__ hidden0,
    const float* __restrict__ gi_e,     // (B*STEPS,3H) incl b_ih_d
    const float* __restrict__ Pm,       // (B,3H,S)
    const float* __restrict__ encP,     // (B*S,H)
    const float* __restrict__ encT,     // (B,H2,S)
    const float* __restrict__ Wa_dec,   // (H,H)
    const float* __restrict__ Wv,       // (H)
    const float* __restrict__ Whh,      // (3H,H)
    const float* __restrict__ bhh,
    const int* __restrict__ lens,
    float* __restrict__ h_store,        // (B*STEPS,H)
    float* __restrict__ ctx_store,      // (B*STEPS,H2)
    float* __restrict__ h_glob,         // (B,H)
    float* __restrict__ dpsG,           // (B,H)
    float* __restrict__ energyG,        // (B,S)
    unsigned* __restrict__ bar) {
  int blk = blockIdx.x, tid = threadIdx.x;
  int j0 = blk * 2;

  __shared__ __align__(16) float ls_whh[6][cH];   // 12KB [jj*3+g]
  __shared__ __align__(16) float ls_wa[2][cH];    // 4KB
  __shared__ __align__(16) float ls_h[cB][cH];    // 32KB
  __shared__ __align__(16) float ls_att[cB][cS];  // 8KB
  __shared__ __align__(16) float ls_dpb[cH];      // 2KB (blocks<64)
  __shared__ float ls_red[cB][16];
  __shared__ float ls_mx[cB], ls_sum[cB];
  __shared__ float ls_A[cB][2][4];                // [b][jj][{dp,r,z,n}] (1..3 used)
  __shared__ float ls_C[cB][2][3];                // gi_ctx

  for (int i = tid; i < 6 * cH; i += 256) {
    int ri = i >> 9, k = i & 511;
    int jj = ri / 3, gg = ri % 3;
    ls_whh[ri][k] = Whh[(size_t)(gg * cH + j0 + jj) * cH + k];
  }
  for (int i = tid; i < 2 * cH; i += 256)
    ls_wa[i >> 9][i & 511] = Wa_dec[(size_t)(j0 + (i >> 9)) * cH + (i & 511)];
  if (tid < 32) {
    int b = tid >> 1, jj = tid & 1;
    cstore(&h_glob[b * cH + j0 + jj], hidden0[b * cH + j0 + jj]);
  }
  float br = 0.f, bz = 0.f, bn = 0.f;
  if (tid < 32) {
    int j = j0 + (tid & 1);
    br = bhh[j]; bz = bhh[cH + j]; bn = bhh[2 * cH + j];
  }
  int lenB = (blk < 64) ? lens[blk >> 2] : 0;
  unsigned g = 0;
  gridbar(bar, 256, g, blk);

  int kt = tid & 15, ot = (tid >> 4) & 3, bt = tid >> 6;
  float* hflat = &ls_h[0][0];

  for (int t = 0; t < cSTEPS; t++) {
    // ---- phase A: dp + gh ----
    for (int i = tid; i < 8192; i += 256)
      hflat[i] = cload(&h_glob[i]);
    __syncthreads();
    {
      const float* w0 = (ot == 0) ? ls_wa[0] : ls_whh[0 * 3 + (ot - 1)];
      const float* w1 = (ot == 0) ? ls_wa[1] : ls_whh[1 * 3 + (ot - 1)];
      float acc[4][2];
#pragma unroll
      for (int i = 0; i < 4; i++) { acc[i][0] = 0.f; acc[i][1] = 0.f; }
      int kbase = kt * 32;
#pragma unroll
      for (int k = 0; k < 32; k += 4) {
        float4 wv0 = *(const float4*)&w0[kbase + k];
        float4 wv1 = *(const float4*)&w1[kbase + k];
#pragma unroll
        for (int bs = 0; bs < 4; bs++) {
          float4 hv = *(const float4*)&ls_h[bt * 4 + bs][kbase + k];
          acc[bs][0] = dot4_(hv, wv0, acc[bs][0]);
          acc[bs][1] = dot4_(hv, wv1, acc[bs][1]);
        }
      }
#pragma unroll
      for (int bs = 0; bs < 4; bs++)
#pragma unroll
        for (int jj = 0; jj < 2; jj++) {
          float v = acc[bs][jj];
          v += __shfl_down(v, 8, 16); v += __shfl_down(v, 4, 16);
          v += __shfl_down(v, 2, 16); v += __shfl_down(v, 1, 16);
          acc[bs][jj] = v;
        }
      if (kt == 0) {
#pragma unroll
        for (int bs = 0; bs < 4; bs++)
#pragma unroll
          for (int jj = 0; jj < 2; jj++) {
            int b = bt * 4 + bs;
            if (ot == 0) cstore(&dpsG[b * cH + j0 + jj], acc[bs][jj]);
            else         ls_A[b][jj][ot] = acc[bs][jj];
          }
      }
    }
    gridbar(bar, 256, g, blk);

    // ---- phase B: energy (blocks 0..63; 4 per batch, 32 s each) ----
    if (blk < 64) {
      int bb = blk >> 2, sq = blk & 3;
      for (int i = tid; i < cH; i += 256) ls_dpb[i] = cload(&dpsG[bb * cH + i]);
      __syncthreads();
      int sl = tid >> 3, k8 = tid & 7;
      int s = sq * 32 + sl;
      const float* ep  = encP + ((size_t)(bb * cS + s)) * cH + k8 * 64;
      const float* dpp = ls_dpb + k8 * 64;
      const float* wvp = Wv + k8 * 64;
      float e = 0.f;
#pragma unroll
      for (int k = 0; k < 64; k += 4) {
        float4 p  = *(const float4*)&ep[k];
        float4 d4 = *(const float4*)&dpp[k];
        float4 w4 = *(const float4*)&wvp[k];
        e = fmaf(w4.x, tanh_(p.x + d4.x), e);
        e = fmaf(w4.y, tanh_(p.y + d4.y), e);
        e = fmaf(w4.z, tanh_(p.z + d4.z), e);
        e = fmaf(w4.w, tanh_(p.w + d4.w), e);
      }
      e += __shfl_down(e, 4, 8); e += __shfl_down(e, 2, 8); e += __shfl_down(e, 1, 8);
      if (k8 == 0) cstore(&energyG[bb * cS + s], (s < lenB) ? e : -1e9f);
    }
    gridbar(bar, 256, g, blk);

    // ---- phase C: softmax (replicated) + ctx/gi_ctx + gates ----
    for (int i = tid; i < cB * cS; i += 256) ls_att[i >> 7][i & 127] = cload(&energyG[i]);
    __syncthreads();
    {
      int sb = tid >> 4, su = tid & 15;
      float mx = -1e30f;
#pragma unroll
      for (int i = 0; i < 8; i++) mx = fmaxf(mx, ls_att[sb][su * 8 + i]);
      ls_red[sb][su] = mx;
      __syncthreads();
      if (su == 0) {
        float m = ls_red[sb][0];
#pragma unroll
        for (int i = 1; i < 16; i++) m = fmaxf(m, ls_red[sb][i]);
        ls_mx[sb] = m;
      }
      __syncthreads();
      float m = ls_mx[sb], ps = 0.f;
#pragma unroll
      for (int i = 0; i < 8; i++) {
        float e = __expf(ls_att[sb][su * 8 + i] - m);
        ls_att[sb][su * 8 + i] = e;
        ps += e;
      }
      __syncthreads();
      ls_red[sb][su] = ps;
      __syncthreads();
      if (su == 0) {
        float s = 0.f;
#pragma unroll
        for (int i = 0; i < 16; i++) s += ls_red[sb][i];
        ls_sum[sb] = 1.f / s;
      }
      __syncthreads();
      for (int i = tid; i < cB * cS; i += 256) {
        int bb2 = i >> 7;
        ls_att[bb2][i & 127] *= ls_sum[bb2];
      }
      __syncthreads();
    }
    // dots: 96 gi_ctx + 64 ctx
    if (tid < 160) {
      const float* rp;
      int b, jj = 0, gg = 0, d = 0;
      if (tid < 96) {
        b = tid / 6; int r6 = tid % 6; gg = r6 >> 1; jj = r6 & 1;
        rp = Pm + ((size_t)b * cH3 + gg * cH + j0 + jj) * cS;
      } else {
        int idx = tid - 96; b = idx >> 2; int dl = idx & 3; d = blk * 4 + dl;
        rp = encT + ((size_t)b * cH2 + d) * cS;
      }
      float a = 0.f;
#pragma unroll
      for (int k = 0; k < cS; k += 4) {
        float4 pv = *(const float4*)&rp[k];
        float4 av = *(const float4*)&ls_att[b][k];
        a = dot4_(pv, av, a);
      }
      if (tid < 96) ls_C[b][jj][gg] = a;
      else ctx_store[((size_t)b * cSTEPS + t) * cH2 + d] = a;
    }
    __syncthreads();
    // gates
    if (tid < 32) {
      int b = tid >> 1, jj = tid & 1, j = j0 + jj;
      size_t row = (size_t)b * cSTEPS + t;
      const float* ge = gi_e + row * cH3;
      float r = sigm_(ge[j] + ls_C[b][jj][0] + ls_A[b][jj][1] + br);
      float z = sigm_(ge[cH + j] + ls_C[b][jj][1] + ls_A[b][jj][2] + bz);
      float n = tanh_(ge[2 * cH + j] + ls_C[b][jj][2] + r * (ls_A[b][jj][3] + bn));
      float hold = ls_h[b][j];
      float hn = (1.f - z) * n + z * hold;
      cstore(&h_glob[b * cH + j], hn);
      h_store[row * cH + j] = hn;
    }
    gridbar(bar, 256, g, blk);
  }
}

// ---------------- transpose enc_out -> encT[b][d][s] ----------------
__global__ void k_transpose_enc(const float* __restrict__ enc_out, float* __restrict__ encT) {
  int bd = blockIdx.x;          // b*H2 + d
  int s = threadIdx.x;          // 128
  int b = bd >> 10, d = bd & 1023;
  encT[(size_t)bd * cS + s] = enc_out[(size_t)(b * cS + s) * cH2 + d];
}

// ---------------- build X (bf16) = [h ; ctx ; e], padded to 2048 rows ----------------
__global__ void k_build_x(const float* __restrict__ h_store, const float* __restrict__ ctx_store,
                          const float* __restrict__ e_store, unsigned short* __restrict__ Xb) {
  const int PAIRS = cMPAD * (cKO / 2);
  for (int idx = blockIdx.x * blockDim.x + threadIdx.x; idx < PAIRS; idx += gridDim.x * blockDim.x) {
    int m = idx / (cKO / 2);
    int k = (idx % (cKO / 2)) * 2;
    float2 v = make_float2(0.f, 0.f);
    if (m < cMOUT) {
      if (k < cH)            v = *(const float2*)&h_store[(size_t)m * cH + k];
      else if (k < cH + cH2) v = *(const float2*)&ctx_store[(size_t)m * cH2 + (k - cH)];
      else                   v = *(const float2*)&e_store[(size_t)m * cE + (k - cH - cH2)];
    }
    ushort2 o; o.x = f2bf(v.x); o.y = f2bf(v.y);
    *(ushort2*)(Xb + (size_t)idx * 2) = o;
  }
}

// ---------------- convert out_W to bf16 ----------------
__global__ void k_cvt_w(const float* __restrict__ Wf, unsigned short* __restrict__ Wb) {
  const int QUADS = cV * cKO / 4;
  for (int idx = blockIdx.x * blockDim.x + threadIdx.x; idx < QUADS; idx += gridDim.x * blockDim.x) {
    float4 v = *(const float4*)&Wf[(size_t)idx * 4];
    ushort4 o; o.x = f2bf(v.x); o.y = f2bf(v.y); o.z = f2bf(v.z); o.w = f2bf(v.w);
    *(ushort4*)(Wb + (size_t)idx * 4) = o;
  }
}

// ---------------- final bf16 MFMA GEMM ----------------
__global__ __launch_bounds__(256) void k_gemm_out(
    const unsigned short* __restrict__ Xb, const unsigned short* __restrict__ Wb,
    const float* __restrict__ bias, float* __restrict__ out) {
  __shared__ __align__(16) unsigned short As[128 * 32];
  __shared__ __align__(16) unsigned short Bs[128 * 32];
  int m0 = blockIdx.x * 128;
  int n0 = blockIdx.y * 128;
  int tid = threadIdx.x;
  int w = tid >> 6, l = tid & 63;
  int wm = (w >> 1) * 64, wn = (w & 1) * 64;
  int quad = l >> 4, lm = l & 15;
  f32x4 acc[4][4];
#pragma unroll
  for (int i = 0; i < 4; i++)
#pragma unroll
    for (int j = 0; j < 4; j++) acc[i][j] = (f32x4){0.f, 0.f, 0.f, 0.f};

  int c0 = tid, c1 = 256 + tid;
  int r0 = c0 >> 2, kc0 = (c0 & 3) * 8;
  int r1 = c1 >> 2, kc1 = (c1 & 3) * 8;
  const unsigned short* ga0 = Xb + (size_t)(m0 + r0) * cKO + kc0;
  const unsigned short* ga1 = Xb + (size_t)(m0 + r1) * cKO + kc1;
  const unsigned short* gb0 = Wb + (size_t)(n0 + r0) * cKO + kc0;
  const unsigned short* gb1 = Wb + (size_t)(n0 + r1) * cKO + kc1;
  unsigned short* la0 = As + (size_t)(w * 64) * 8;
  unsigned short* la1 = As + (size_t)(256 + w * 64) * 8;
  unsigned short* lb0 = Bs + (size_t)(w * 64) * 8;
  unsigned short* lb1 = Bs + (size_t)(256 + w * 64) * 8;

  for (int k0 = 0; k0 < cKO; k0 += 32) {
    __syncthreads();
    GLD16(ga0 + k0, la0);
    GLD16(ga1 + k0, la1);
    GLD16(gb0 + k0, lb0);
    GLD16(gb1 + k0, lb1);
    __syncthreads();
    bf16x8 af[4], bfr[4];
#pragma unroll
    for (int i = 0; i < 4; i++) {
      af[i]  = *(const bf16x8*)(As + (size_t)(wm + i * 16 + lm) * 32 + quad * 8);
      bfr[i] = *(const bf16x8*)(Bs + (size_t)(wn + i * 16 + lm) * 32 + quad * 8);
    }
#pragma unroll
    for (int i = 0; i < 4; i++)
#pragma unroll
      for (int j = 0; j < 4; j++)
        acc[i][j] = __builtin_amdgcn_mfma_f32_16x16x32_bf16(af[i], bfr[j], acc[i][j], 0, 0, 0);
  }
  for (int i = 0; i < 4; i++) {
    int gmb = m0 + wm + i * 16 + quad * 4;
    for (int j = 0; j < 4; j++) {
      int gn = n0 + wn + j * 16 + lm;
      float bv = bias[gn];
#pragma unroll
      for (int r = 0; r < 4; r++) {
        int gm = gmb + r;
        if (gm < cMOUT) out[(size_t)gm * cV + gn] = acc[i][j][r] + bv;
      }
    }
  }
}

extern "C" void kernel_launch(void* const* d_in, const int* in_sizes, int n_in,
                              void* d_out, int out_size, void* d_ws, size_t ws_size,
                              hipStream_t stream) {
  const int*   src      = (const int*)d_in[0];
  const int*   lens     = (const int*)d_in[1];
  const int*   tgt      = (const int*)d_in[2];
  const float* enc_emb  = (const float*)d_in[3];
  const float* W_ih_f   = (const float*)d_in[4];
  const float* W_hh_f   = (const float*)d_in[5];
  const float* b_ih_f   = (const float*)d_in[6];
  const float* b_hh_f   = (const float*)d_in[7];
  const float* W_ih_b   = (const float*)d_in[8];
  const float* W_hh_b   = (const float*)d_in[9];
  const float* b_ih_b   = (const float*)d_in[10];
  const float* b_hh_b   = (const float*)d_in[11];
  const float* bridge_W = (const float*)d_in[12];
  const float* bridge_b = (const float*)d_in[13];
  const float* dec_emb  = (const float*)d_in[14];
  const float* Wa_enc   = (const float*)d_in[15];
  const float* Wa_dec   = (const float*)d_in[16];
  const float* Wv       = (const float*)d_in[17];
  const float* W_ih_d   = (const float*)d_in[18];
  const float* W_hh_d   = (const float*)d_in[19];
  const float* b_ih_d   = (const float*)d_in[20];
  const float* b_hh_d   = (const float*)d_in[21];
  const float* out_W    = (const float*)d_in[22];
  const float* out_b    = (const float*)d_in[23];
  float* out = (float*)d_out;

  float* ws = (float*)d_ws;
  float* emb       = ws;                       // 16*128*256   (reused as aux after gi GEMMs)
  float* emb_rev   = emb + 524288;
  float* gi_f      = emb_rev + 524288;         // 16*128*1536
  float* gi_b      = gi_f + 3145728;
  float* enc_out   = gi_b + 3145728;           // 16*128*1024
  float* hcat      = enc_out + 2097152;        // 16*1024
  float* hidden0   = hcat + 16384;             // 16*512
  float* encP      = hidden0 + 8192;           // 16*128*512
  float* encT      = encP + 1048576;           // 16*1024*128
  float* Pm        = encT + 2097152;           // 16*1536*128
  float* gi_e      = Pm + 3145728;             // 16*127*1536
  float* e_store   = gi_e + 3121152;           // 16*127*256
  float* h_store   = e_store + 520192;         // 16*127*512
  float* ctx_store = h_store + 1040384;        // 16*127*1024
  unsigned short* Xb = (unsigned short*)(ctx_store + 2080768); // 2048*1792 bf16
  unsigned short* Wb = Xb + (size_t)2048 * 1792;               // 32000*1792 bf16

  // aux region reuses emb (dead after the gi GEMMs)
  float* h_globE = emb;              // 16384 (2 dirs x 16 x 512)
  float* h_glob  = emb + 16384;      // 8192
  float* dpsG    = emb + 24576;      // 8192
  float* energyG = emb + 32768;      // 2048
  unsigned* barE = (unsigned*)(emb + 34816);   // flags[256*16]+gen[4*16]
  unsigned* barD = barE + cBARSZ;

  // embeddings
  k_embed_enc<<<cB * cS, cE, 0, stream>>>(src, lens, enc_emb, emb, emb_rev);
  k_embed_dec<<<cB * cSTEPS, cE, 0, stream>>>(tgt, dec_emb, e_store);
  // encoder gi (both dirs)  — read emb/emb_rev
  k_gemm_nt_f32<<<dim3(16, 24, 1), 256, 0, stream>>>(emb, cE, 0, W_ih_f, cE, 0,
      gi_f, cH3, 0, cB * cS, cH3, cE, b_ih_f, 0);
  k_gemm_nt_f32<<<dim3(16, 24, 1), 256, 0, stream>>>(emb_rev, cE, 0, W_ih_b, cE, 0,
      gi_b, cH3, 0, cB * cS, cH3, cE, b_ih_b, 0);
  // barriers zeroed AFTER gi GEMMs (aux aliases emb)
  k_zero<<<33, 256, 0, stream>>>(barE, 2 * cBARSZ);
  // cooperative encoder scan
  {
    void* args[] = {(void*)&gi_f, (void*)&gi_b, (void*)&W_hh_f, (void*)&W_hh_b,
                    (void*)&b_hh_f, (void*)&b_hh_b, (void*)&lens, (void*)&enc_out,
                    (void*)&hcat, (void*)&h_globE, (void*)&barE};
    hipLaunchCooperativeKernel((void*)k_enc_coop, dim3(256), dim3(256), args, 0, stream);
  }
  // bridge -> hidden0 (tanh)
  k_gemm_nt_f32<<<dim3(1, 8, 1), 256, 0, stream>>>(hcat, cH2, 0, bridge_W, cH2, 0,
      hidden0, cH, 0, cB, cH, cH2, bridge_b, 1);
  // encP = enc_out @ Wa_enc^T
  k_gemm_nt_f32<<<dim3(16, 8, 1), 256, 0, stream>>>(enc_out, cH2, 0, Wa_enc, cH2, 0,
      encP, cH, 0, cB * cS, cH, cH2, nullptr, 0);
  // encT transpose
  k_transpose_enc<<<cB * cH2, cS, 0, stream>>>(enc_out, encT);
  // P[b] = W_ih_d[:,E:] @ enc_out[b]^T
  k_gemm_nt_f32<<<dim3(12, 2, 16), 256, 0, stream>>>(W_ih_d + cE, cE + cH2, 0,
      enc_out, cH2, (long)cS * cH2, Pm, cS, (long)cH3 * cS, cH3, cS, cH2, nullptr, 0);
  // gi_e = e @ W_ih_d[:,:E]^T + b_ih_d
  k_gemm_nt_f32<<<dim3(16, 24, 1), 256, 0, stream>>>(e_store, cE, 0, W_ih_d, cE + cH2, 0,
      gi_e, cH3, 0, cB * cSTEPS, cH3, cE, b_ih_d, 0);
  // cooperative decoder scan
  {
    void* args[] = {(void*)&hidden0, (void*)&gi_e, (void*)&Pm, (void*)&encP,
                    (void*)&encT, (void*)&Wa_dec, (void*)&Wv, (void*)&W_hh_d,
                    (void*)&b_hh_d, (void*)&lens, (void*)&h_store, (void*)&ctx_store,
                    (void*)&h_glob, (void*)&dpsG, (void*)&energyG, (void*)&barD};
    hipLaunchCooperativeKernel((void*)k_dec_coop, dim3(256), dim3(256), args, 0, stream);
  }
  // assemble X, convert W, big GEMM
  k_build_x<<<2048, 256, 0, stream>>>(h_store, ctx_store, e_store, Xb);
  k_cvt_w<<<4096, 256, 0, stream>>>(out_W, Wb);
  k_gemm_out<<<dim3(16, 250, 1), 256, 0, stream>>>(Xb, Wb, out_b, out);
}